// Round 4
// baseline (232.316 us; speedup 1.0000x reference)
//
#include <hip/hip_runtime.h>
#include <stdint.h>

// MultiBoxLoss: B=64 rows, D=65536 anchors, ~2% positives.
// R11 = R10 algorithm with hardened inline asm (the R10 bench killed the
// container twice with no error -> prime suspects were (a) HIP uint4 structs
// passed to "v" asm constraints (not a guaranteed-legal register type) and
// (b) missing early-clobber on asm outputs (output quad may alias the
// address pair). Both fixed: ext_vector_type(4) operands, "=&v" everywhere.
//
// R10 design recap (untested): R9 counters showed kernel 68us at 13.5%
// occupancy -> ~50us was the 64-block Phase-B tail whose relaxed-ATOMIC-load
// loops serialize at ~1200cy L3 latency x27 iters x2 passes. Fix: Phase A
// (which holds every candidate in registers) builds per row, via
// device-scope atomics:
//   - hist[4096] u32 counts (atomicAdd, returned value = value slot)
//   - bsum[4096] u64 fixed-point (2^38) softplus sums (integer adds commute
//     -> deterministic, order-independent)
//   - bval[4096][32] f32 value slots (sc0sc1 write-through stores)
// Phase B never touches the candidate stream: one batched 64B sc-load round
// for its 16 hist bins, suffix scan, one batched 128B round for 16 bin
// sums, one parallel-lane load of <=32 bin-J values, rank-select. Block
// partials (SL1/BCE/NP) and row results (NEG/K) accumulate into 5 packed
// global scalars -> Phase C is one 32-B read by the done-elected block.
// Elections stay RELAXED agent-scope (R9-proven: no cache-wide wbl2/inv);
// the pre-election __syncthreads drains vmcnt so all atomics/sc1 stores are
// at L3 before the counter RMW lands there.
// memset per iteration: [0, 3.0 MiB) = counters + scalars + NPR + hist + bsum.

#define B_ 64
#define D_ 65536
#define NEGPOS 3
#define BPR 16                 // blocks per row
#define NBLK (B_ * BPR)        // 1024
#define CHUNK (D_ / BPR)       // 4096 elements per block
#define XC 1.25f               // candidate cutoff (P(x>=XC)~10.6% per row)
#define HBINS 4096             // histogram bins over x in [XC, XC+XRANGE)
#define XRANGE 5.0f
#define CAP 32                 // per-bin value slots (hot bin ~15; P(>32) tiny)

#define FXS 274877906944.0     // 2^38 fixed-point scale
#define FXI (1.0 / 274877906944.0)

typedef unsigned long long ull;
typedef unsigned uint32x4 __attribute__((ext_vector_type(4)));  // legal "v" type

// ---------------- ws layout (bytes) ----------------
#define OFF_CNT   0            // u32 rowcnt[64] + u32 done (260 B)   [zeroed]
#define OFF_SCAL  512          // 32B: NPTOT u32, KTOT u32, SL1T u64, BCET u64, NEGT u64 [zeroed]
#define OFF_NPR   1024         // u32[64]                             [zeroed]
#define OFF_HIST  4096         // u32[64][4096] = 1 MiB               [zeroed]
#define OFF_BSUM  1052672      // u64[64][4096] = 2 MiB               [zeroed]
#define ZERO_BYTES 3149824     // one contiguous memset
#define OFF_BVAL  4194304      // f32[64][4096][32] = 32 MiB          [not zeroed: guarded by hist]

// ---- agent-coherent (sc0 sc1) relaxed ops: per-instruction coherence,
// no cache-wide wbl2/inv (R9-proven correct+fast on this HW).
__device__ __forceinline__ void stgF(float* p, float v) {
    __hip_atomic_store(p, v, __ATOMIC_RELAXED, __HIP_MEMORY_SCOPE_AGENT);
}
__device__ __forceinline__ float ldgF(const float* p) {
    return __hip_atomic_load(p, __ATOMIC_RELAXED, __HIP_MEMORY_SCOPE_AGENT);
}
__device__ __forceinline__ unsigned ldgU(const unsigned* p) {
    return __hip_atomic_load(p, __ATOMIC_RELAXED, __HIP_MEMORY_SCOPE_AGENT);
}

// ---- batched L2-bypass loads: issue N dwordx4 then ONE waitcnt, all inside
// a single asm block. Outputs are EARLY-CLOBBER ("=&v") so they can never
// alias the address pair; consumers read the outputs -> true data dep, no
// hoisting hazard. These dodge the atomic-load serialization that made R9's
// Phase B latency-bound.
__device__ __forceinline__ void ldg64B_sc(const void* p,
                                          uint32x4& a, uint32x4& b,
                                          uint32x4& c, uint32x4& d) {
    asm volatile(
        "global_load_dwordx4 %0, %4, off sc0 sc1\n\t"
        "global_load_dwordx4 %1, %4, off offset:16 sc0 sc1\n\t"
        "global_load_dwordx4 %2, %4, off offset:32 sc0 sc1\n\t"
        "global_load_dwordx4 %3, %4, off offset:48 sc0 sc1\n\t"
        "s_waitcnt vmcnt(0)"
        : "=&v"(a), "=&v"(b), "=&v"(c), "=&v"(d)
        : "v"(p)
        : "memory");
}
__device__ __forceinline__ void ldg128B_sc(const void* p,
                                           uint32x4& a, uint32x4& b,
                                           uint32x4& c, uint32x4& d,
                                           uint32x4& e, uint32x4& f,
                                           uint32x4& g, uint32x4& h) {
    asm volatile(
        "global_load_dwordx4 %0, %8, off sc0 sc1\n\t"
        "global_load_dwordx4 %1, %8, off offset:16 sc0 sc1\n\t"
        "global_load_dwordx4 %2, %8, off offset:32 sc0 sc1\n\t"
        "global_load_dwordx4 %3, %8, off offset:48 sc0 sc1\n\t"
        "global_load_dwordx4 %4, %8, off offset:64 sc0 sc1\n\t"
        "global_load_dwordx4 %5, %8, off offset:80 sc0 sc1\n\t"
        "global_load_dwordx4 %6, %8, off offset:96 sc0 sc1\n\t"
        "global_load_dwordx4 %7, %8, off offset:112 sc0 sc1\n\t"
        "s_waitcnt vmcnt(0)"
        : "=&v"(a), "=&v"(b), "=&v"(c), "=&v"(d),
          "=&v"(e), "=&v"(f), "=&v"(g), "=&v"(h)
        : "v"(p)
        : "memory");
}
__device__ __forceinline__ void ldg32B_sc(const void* p, uint32x4& a, uint32x4& b) {
    asm volatile(
        "global_load_dwordx4 %0, %2, off sc0 sc1\n\t"
        "global_load_dwordx4 %1, %2, off offset:16 sc0 sc1\n\t"
        "s_waitcnt vmcnt(0)"
        : "=&v"(a), "=&v"(b)
        : "v"(p)
        : "memory");
}

__device__ __forceinline__ float softplus_f(float x) {   // bce for t=0
    return fmaxf(x, 0.0f) + log1pf(expf(-fabsf(x)));
}

__device__ __forceinline__ int bin_of_x(float x) {
    int b = (int)((x - XC) * ((float)HBINS / XRANGE));
    return max(0, min(HBINS - 1, b));
}

__device__ __forceinline__ float smooth_l1_4(float4 a, float4 b) {
    float s = 0.0f, d, ad;
    d = a.x - b.x; ad = fabsf(d); s += (ad < 1.0f) ? 0.5f * d * d : ad - 0.5f;
    d = a.y - b.y; ad = fabsf(d); s += (ad < 1.0f) ? 0.5f * d * d : ad - 0.5f;
    d = a.z - b.z; ad = fabsf(d); s += (ad < 1.0f) ? 0.5f * d * d : ad - 0.5f;
    d = a.w - b.w; ad = fabsf(d); s += (ad < 1.0f) ? 0.5f * d * d : ad - 0.5f;
    return s;
}

__device__ __forceinline__ double wredD(double v) {
#pragma unroll
    for (int o = 32; o > 0; o >>= 1) v += __shfl_down(v, o, 64);
    return v;
}
__device__ __forceinline__ int wredI(int v) {
#pragma unroll
    for (int o = 32; o > 0; o >>= 1) v += __shfl_down(v, o, 64);
    return v;
}
__device__ __forceinline__ ull wredU64(ull v) {
#pragma unroll
    for (int o = 32; o > 0; o >>= 1) v += __shfl_down(v, o, 64);
    return v;
}

__device__ __forceinline__ int blockSumI(int v, int* sh) {
    int w = wredI(v);
    const int lane = threadIdx.x & 63, wid = threadIdx.x >> 6;
    __syncthreads();
    if (lane == 0) sh[wid] = w;
    __syncthreads();
    return sh[0] + sh[1] + sh[2] + sh[3];
}

__global__ void __launch_bounds__(256)
mbl_fused(const float4* __restrict__ loc4, const float* __restrict__ conf,
          const float4* __restrict__ loct4, const int* __restrict__ conft,
          unsigned char* __restrict__ ws, float* __restrict__ out)
{
    __shared__ unsigned short lpos[CHUNK];   // 8 KB: positive-index compaction
    __shared__ unsigned wtot[4], wsuf[4];
    __shared__ double wrD[4];
    __shared__ ull wrU[4];
    __shared__ float sVals[CAP];
    __shared__ unsigned shJ, shRemJ, shHJ, shNP, shT;
    __shared__ int shI[4];
    __shared__ int shLast;

    const int block = blockIdx.x;
    const int row = block >> 4;          // BPR = 16
    const int base = block * CHUNK;
    const int lane = threadIdx.x & 63, wid = threadIdx.x >> 6;

    unsigned* rowhist = (unsigned*)(ws + OFF_HIST) + (size_t)row * HBINS;
    ull*      rowbsum = (ull*)(ws + OFF_BSUM) + (size_t)row * HBINS;
    float*    rowbval = (float*)(ws + OFF_BVAL) + (size_t)row * HBINS * CAP;

    // ===================== Phase A: per-chunk pass =====================
    {
        const float4* c4 = (const float4*)(conf + base);
        const int4*   t4 = (const int4*)(conft + base);

        float4 xv[4]; int4 tv[4];
#pragma unroll
        for (int it = 0; it < 4; it++) {
            const int g = threadIdx.x + it * 256;
            xv[it] = c4[g];
            tv[it] = t4[g];
        }

        double bcp = 0.0;
        unsigned cntp = 0;
#pragma unroll
        for (int it = 0; it < 4; it++) {
#pragma unroll
            for (int c = 0; c < 4; c++) {
                float x = (c == 0) ? xv[it].x : (c == 1) ? xv[it].y : (c == 2) ? xv[it].z : xv[it].w;
                int   t = (c == 0) ? tv[it].x : (c == 1) ? tv[it].y : (c == 2) ? tv[it].z : tv[it].w;
                if (t > 0) { cntp++; bcp += (double)(softplus_f(x) - x); }
                else if (x >= XC) {
                    const int b = bin_of_x(x);
                    const unsigned slot = atomicAdd(rowhist + b, 1u);
                    atomicAdd(rowbsum + b, (ull)((double)softplus_f(x) * FXS + 0.5));
                    if (slot < CAP) stgF(rowbval + (size_t)b * CAP + slot, x);
                }
            }
        }

        // compact positive indices (for the sl1 gather)
        unsigned incl = cntp;
#pragma unroll
        for (int o = 1; o < 64; o <<= 1) {
            unsigned v = __shfl_up(incl, o, 64);
            if (lane >= o) incl += v;
        }
        unsigned excl = incl - cntp;
        if (lane == 63) wtot[wid] = incl;
        __syncthreads();
        unsigned wbase = 0;
        for (int w = 0; w < wid; w++) wbase += wtot[w];
        const unsigned totp = wtot[0] + wtot[1] + wtot[2] + wtot[3];
        unsigned offp = excl + wbase;

#pragma unroll
        for (int it = 0; it < 4; it++) {
#pragma unroll
            for (int c = 0; c < 4; c++) {
                int t = (c == 0) ? tv[it].x : (c == 1) ? tv[it].y : (c == 2) ? tv[it].z : tv[it].w;
                const int li = (threadIdx.x + it * 256) * 4 + c;
                if (t > 0) lpos[offp++] = (unsigned short)li;
            }
        }
        __syncthreads();

        double sl1 = 0.0;
        for (unsigned i = threadIdx.x; i < totp; i += 256) {
            const int e = base + (int)lpos[i];
            sl1 += (double)smooth_l1_4(loc4[e], loct4[e]);
        }

        double s1 = wredD(sl1), s2 = wredD(bcp);
        if (lane == 0) { wrD[wid] = s1; wrU[wid] = (ull)(s2 * FXS + 0.5); }
        __syncthreads();
        if (threadIdx.x == 0) {
            double SL1b = wrD[0] + wrD[1] + wrD[2] + wrD[3];
            ull    BCEb = wrU[0] + wrU[1] + wrU[2] + wrU[3];
            atomicAdd((ull*)(ws + OFF_SCAL + 8), (ull)(SL1b * FXS + 0.5));  // SL1T
            atomicAdd((ull*)(ws + OFF_SCAL + 16), BCEb);                    // BCET
            atomicAdd((unsigned*)(ws + OFF_SCAL), totp);                    // NPTOT
            atomicAdd((unsigned*)(ws + OFF_NPR) + row, totp);               // NPR[row]
        }
    }

    // ---- row-last election (vmcnt drained by the barrier -> all atomics and
    // sc1 stores are at L3 before the counter RMW lands there)
    __syncthreads();
    if (threadIdx.x == 0) {
        unsigned old = __hip_atomic_fetch_add(
            (unsigned*)(ws + OFF_CNT) + row, 1u,
            __ATOMIC_RELAXED, __HIP_MEMORY_SCOPE_AGENT);
        shLast = (old == BPR - 1) ? 1 : 0;
    }
    __syncthreads();
    if (!shLast) return;

    // ===================== Phase B: row exact top-k (64 concurrent blocks) =====================
    // my 16 hist bins, one batched load round
    uint32x4 h0, h1, h2, h3;
    ldg64B_sc(rowhist + (size_t)threadIdx.x * 16, h0, h1, h2, h3);
    unsigned hb[16] = {h0.x,h0.y,h0.z,h0.w, h1.x,h1.y,h1.z,h1.w,
                       h2.x,h2.y,h2.z,h2.w, h3.x,h3.y,h3.z,h3.w};
    unsigned s16 = 0;
#pragma unroll
    for (int j = 0; j < 16; j++) s16 += hb[j];
    unsigned suf = s16;
#pragma unroll
    for (int o = 1; o < 64; o <<= 1) {
        unsigned v = __shfl_down(suf, o, 64);
        if (lane + o < 64) suf += v;
    }
    if (lane == 0) wsuf[wid] = suf;
    if (threadIdx.x == 0) shNP = ldgU((const unsigned*)(ws + OFF_NPR) + row);
    __syncthreads();
    unsigned addw = 0;
    for (int w = wid + 1; w < 4; w++) addw += wsuf[w];
    suf += addw;                          // inclusive suffix over all 256 chunks
    if (threadIdx.x == 0) shT = suf;      // total candidate count n
    const unsigned sufx = suf - s16;      // bins strictly above my chunk

    const int np = (int)shNP;
    long long k = (long long)np * NEGPOS;
    if (k > D_) k = D_;
    long long negs = (long long)D_ - np;
    if (k > negs) k = negs;

    if ((long long)sufx < k && (long long)suf >= k) {
        long long cum = sufx;
        const int b0i = threadIdx.x * 16;
#pragma unroll
        for (int j = 15; j >= 0; j--) {
            cum += hb[j];
            if (cum >= k) {
                shJ = (unsigned)(b0i + j);
                shRemJ = (unsigned)(k - (cum - (long long)hb[j]));
                shHJ = hb[j];
                break;
            }
        }
    }
    __syncthreads();
    const unsigned n = shT;

    if (threadIdx.x == 0 && k > 0)
        atomicAdd((unsigned*)(ws + OFF_SCAL) + 1, (unsigned)k);   // KTOT

    bool skip = (k <= 0);
    bool fb = false;
    if (!skip) {
        if ((long long)n < k) fb = true;          // not enough candidates >= XC
        else if (shHJ > CAP) fb = true;           // bin-J slot overflow (rare)
    }

    if (!skip && !fb) {
        const unsigned J = shJ, remJ = shRemJ, cnt = shHJ;

        // masked fixed-point sum of bins > J: one batched 128B round
        uint32x4 b0, b1, b2, b3, b4, b5, b6, b7;
        ldg128B_sc(rowbsum + (size_t)threadIdx.x * 16,
                   b0, b1, b2, b3, b4, b5, b6, b7);
        ull vb[16] = {
            ((ull)b0.y << 32) | b0.x, ((ull)b0.w << 32) | b0.z,
            ((ull)b1.y << 32) | b1.x, ((ull)b1.w << 32) | b1.z,
            ((ull)b2.y << 32) | b2.x, ((ull)b2.w << 32) | b2.z,
            ((ull)b3.y << 32) | b3.x, ((ull)b3.w << 32) | b3.z,
            ((ull)b4.y << 32) | b4.x, ((ull)b4.w << 32) | b4.z,
            ((ull)b5.y << 32) | b5.x, ((ull)b5.w << 32) | b5.z,
            ((ull)b6.y << 32) | b6.x, ((ull)b6.w << 32) | b6.z,
            ((ull)b7.y << 32) | b7.x, ((ull)b7.w << 32) | b7.z };
        ull accS = 0;
        const int bb0 = threadIdx.x * 16;
#pragma unroll
        for (int j = 0; j < 16; j++)
            if ((unsigned)(bb0 + j) > J) accS += vb[j];
        ull wS = wredU64(accS);
        if (lane == 0) wrU[wid] = wS;

        // bin-J values: one parallel-lane load round (cnt <= 32)
        if (wid == 0 && lane < (int)cnt)
            sVals[lane] = ldgF(rowbval + (size_t)J * CAP + lane);
        __syncthreads();

        double cj = 0.0;
        if (threadIdx.x < (int)cnt) {
            const float xi = sVals[threadIdx.x];
            unsigned r = 0;
            for (unsigned l = 0; l < cnt; l++) {
                const float xl = sVals[l];
                r += (xl > xi || (xl == xi && l < (unsigned)threadIdx.x)) ? 1u : 0u;
            }
            if (r < remJ) cj = (double)softplus_f(xi);
        }
        double cjw = wredD(cj);
        if (lane == 0) wrD[wid] = cjw;
        __syncthreads();
        if (threadIdx.x == 0) {
            ull Sgt = wrU[0] + wrU[1] + wrU[2] + wrU[3];
            double CJ = wrD[0] + wrD[1] + wrD[2] + wrD[3];
            atomicAdd((ull*)(ws + OFF_SCAL + 24), Sgt + (ull)(CJ * FXS + 0.5)); // NEGT
        }
    } else if (!skip && fb) {
        // exact uint-bisection over the full row (bit-exact threshold);
        // conf/conft are kernel inputs -> plain cached loads fine
        const float* rowc = conf + row * D_;
        const int*   rowt = conft + row * D_;
        unsigned lo = 0u, hi = 0xFFFFFFFFu;
        for (int it = 0; it < 32; it++) {
            const unsigned mid = lo + ((hi - lo) >> 1);
            unsigned um = (mid & 0x80000000u) ? (mid & 0x7FFFFFFFu) : ~mid;
            float fm = __uint_as_float(um);
            int c = 0;
            for (int i = threadIdx.x; i < D_; i += 256)
                if (rowt[i] <= 0 && rowc[i] > fm) c++;
            const int tot = blockSumI(c, shI);
            if ((long long)tot >= k) lo = mid; else hi = mid;
        }
        unsigned uT = (hi & 0x80000000u) ? (hi & 0x7FFFFFFFu) : ~hi;
        float xT = __uint_as_float(uT);
        int c = 0;
        double acc = 0.0;
        for (int i = threadIdx.x; i < D_; i += 256) {
            if (rowt[i] <= 0) {
                float x = rowc[i];
                if (x > xT) { c++; acc += (double)softplus_f(x); }
            }
        }
        int rem = (int)(k - (long long)blockSumI(c, shI));
        double t = wredD(acc);
        if (lane == 0) wrD[wid] = t;
        __syncthreads();
        if (threadIdx.x == 0) {
            double tot = wrD[0] + wrD[1] + wrD[2] + wrD[3] +
                         (double)rem * (double)softplus_f(xT);
            atomicAdd((ull*)(ws + OFF_SCAL + 24), (ull)(tot * FXS + 0.5));  // NEGT
        }
    }
    // skip path: k<=0 contributes nothing

    // ---- done-row election
    __syncthreads();
    if (threadIdx.x == 0) {
        unsigned old = __hip_atomic_fetch_add(
            (unsigned*)(ws + OFF_CNT) + B_, 1u,
            __ATOMIC_RELAXED, __HIP_MEMORY_SCOPE_AGENT);
        shLast = (old == B_ - 1) ? 1 : 0;
    }
    __syncthreads();
    if (!shLast) return;

    // ===================== Phase C: final scalars (one 32-B read) =====================
    if (threadIdx.x == 0) {
        uint32x4 sa, sb;
        ldg32B_sc(ws + OFF_SCAL, sa, sb);
        const double Np  = (double)sa.x;
        const double Kt  = (double)sa.y;
        const double SL1 = (double)(((ull)sa.w << 32) | sa.z) * FXI;
        const double BCE = (double)(((ull)sb.y << 32) | sb.x) * FXI;
        const double NSUM = (double)(((ull)sb.w << 32) | sb.z) * FXI;
        double out0 = (Np > 0.0) ? (SL1 / (4.0 * Np)) / Np : 0.0;
        double denom = Np + Kt;
        double out1 = (Np > 0.0 && denom > 0.0) ? ((BCE + NSUM) / denom) / Np : 0.0;
        out[0] = (float)out0;
        out[1] = (float)out1;
    }
}

extern "C" void kernel_launch(void* const* d_in, const int* in_sizes, int n_in,
                              void* d_out, int out_size, void* d_ws, size_t ws_size,
                              hipStream_t stream)
{
    const float4* loc4  = (const float4*)d_in[0];   // (B,D,4) f32
    const float*  conf  = (const float*)d_in[1];    // (B,D,1) f32
    const float4* loct4 = (const float4*)d_in[2];   // (B,D,4) f32
    const int*    conft = (const int*)d_in[3];      // (B,D)   i32
    unsigned char* ws = (unsigned char*)d_ws;
    float* out = (float*)d_out;

    // zero counters + scalars + NPR + hist + bsum (ws is poisoned each iter)
    hipMemsetAsync(ws, 0, ZERO_BYTES, stream);
    mbl_fused<<<dim3(NBLK), dim3(256), 0, stream>>>(loc4, conf, loct4, conft, ws, out);
}

// Round 5
// 227.813 us; speedup vs baseline: 1.0198x; 1.0198x over previous
//
#include <hip/hip_runtime.h>
#include <stdint.h>

// MultiBoxLoss: B=64 rows, D=65536 anchors, ~2% positives.
// R12: R9 Phase A (proven ~15us) + Phase B rebuilt on batched sc-loads with
// register-resident candidates. History:
//  - R9 (68us): Phase B looped __hip_atomic_load -> ~27 serialized L3 round
//    trips x2 passes = ~50us tail (occupancy 13.5%).
//  - R11 (100us): moved binning into Phase A via per-candidate global atomics
//    -> 40MB of fine-grained HBM writes (hist/bsum line dirtying) + dependent
//    atomic chains in the hot loop. Reverted.
// R12 Phase B: 16 threads per segment; each thread pulls its 160B slice of
// the segment's compacted candidates in ONE asm block (10 x dwordx4 sc0sc1,
// single vmcnt(0)) -> whole row (~6.9k floats) in registers in ~1 L3 round
// trip. LDS histogram + parallel suffix scan (R7-proven) -> threshold bin J;
// selection pass re-reads REGISTERS (no global). Phase C reads all partials
// with the same batched trick. Segment cap 640 (>10 sigma over mean 434)
// guards register residency; overflow/mass-tie -> bisection fallback.
// Elections stay RELAXED agent-scope (R9-proven: no cache-wide wbl2/inv);
// pre-election __syncthreads drains vmcnt so sc1 data is at L3 before the
// counter RMW lands there. memset/iter: 260B of election counters only.

#define B_ 64
#define D_ 65536
#define NEGPOS 3
#define BPR 16                 // blocks per row
#define NBLK (B_ * BPR)        // 1024
#define CHUNK (D_ / BPR)       // 4096 elements per block
#define XC 1.25f               // candidate cutoff (P(x>=XC)~10.6% per row)
#define HBINS 4096             // histogram bins over x in [XC, XC+XRANGE)
#define XRANGE 5.0f
#define CJCAP 1024             // bin-J gather capacity (expect ~8)
#define RQ 10                  // dwordx4 per thread in Phase B (40 floats)
#define RCAP (16 * RQ * 4)     // 640: per-segment candidate cap (mean 434, sd 20)

typedef unsigned long long ull;
typedef unsigned uint32x4 __attribute__((ext_vector_type(4)));  // legal "v" type

// ---------------- ws layout (bytes) ----------------
#define OFF_SL1P   0           // double[NBLK]
#define OFF_BCEP   8192        // double[NBLK]
#define OFF_NP     16384       // u32[NBLK]
#define OFF_CC     20480       // u32[NBLK]
#define OFF_NEGSUM 24576       // double[64]
#define OFF_KSEL   25088       // int[64]
#define OFF_CNT    25344       // u32 rowcnt[64] + u32 done  [zeroed per iter]
#define OFF_CAND   32768       // float[NBLK][CHUNK] = 16 MiB

// ---- agent-coherent (sc0 sc1) relaxed ops: per-instruction coherence,
// no cache-wide wbl2/inv (R9-proven correct+fast on this HW).
__device__ __forceinline__ void stgF(float* p, float v) {
    __hip_atomic_store(p, v, __ATOMIC_RELAXED, __HIP_MEMORY_SCOPE_AGENT);
}
__device__ __forceinline__ void stgU(unsigned* p, unsigned v) {
    __hip_atomic_store(p, v, __ATOMIC_RELAXED, __HIP_MEMORY_SCOPE_AGENT);
}
__device__ __forceinline__ void stgI(int* p, int v) {
    __hip_atomic_store(p, v, __ATOMIC_RELAXED, __HIP_MEMORY_SCOPE_AGENT);
}
__device__ __forceinline__ void stgD(double* p, double v) {
    __hip_atomic_store(p, v, __ATOMIC_RELAXED, __HIP_MEMORY_SCOPE_AGENT);
}
__device__ __forceinline__ unsigned ldgU(const unsigned* p) {
    return __hip_atomic_load(p, __ATOMIC_RELAXED, __HIP_MEMORY_SCOPE_AGENT);
}

// ---- batched L2-bypass loads: issue N dwordx4 then ONE waitcnt inside a
// single asm block (early-clobber outputs; consumers read outputs -> data
// dep). This is what __hip_atomic_load loops can't do: N loads in flight.
__device__ __forceinline__ void ldg160B_sc(const void* p,
        uint32x4& a0, uint32x4& a1, uint32x4& a2, uint32x4& a3, uint32x4& a4,
        uint32x4& a5, uint32x4& a6, uint32x4& a7, uint32x4& a8, uint32x4& a9) {
    asm volatile(
        "global_load_dwordx4 %0, %10, off sc0 sc1\n\t"
        "global_load_dwordx4 %1, %10, off offset:16 sc0 sc1\n\t"
        "global_load_dwordx4 %2, %10, off offset:32 sc0 sc1\n\t"
        "global_load_dwordx4 %3, %10, off offset:48 sc0 sc1\n\t"
        "global_load_dwordx4 %4, %10, off offset:64 sc0 sc1\n\t"
        "global_load_dwordx4 %5, %10, off offset:80 sc0 sc1\n\t"
        "global_load_dwordx4 %6, %10, off offset:96 sc0 sc1\n\t"
        "global_load_dwordx4 %7, %10, off offset:112 sc0 sc1\n\t"
        "global_load_dwordx4 %8, %10, off offset:128 sc0 sc1\n\t"
        "global_load_dwordx4 %9, %10, off offset:144 sc0 sc1\n\t"
        "s_waitcnt vmcnt(0)"
        : "=&v"(a0), "=&v"(a1), "=&v"(a2), "=&v"(a3), "=&v"(a4),
          "=&v"(a5), "=&v"(a6), "=&v"(a7), "=&v"(a8), "=&v"(a9)
        : "v"(p)
        : "memory");
}
__device__ __forceinline__ void ldg32B_sc(const void* p, uint32x4& a, uint32x4& b) {
    asm volatile(
        "global_load_dwordx4 %0, %2, off sc0 sc1\n\t"
        "global_load_dwordx4 %1, %2, off offset:16 sc0 sc1\n\t"
        "s_waitcnt vmcnt(0)"
        : "=&v"(a), "=&v"(b)
        : "v"(p)
        : "memory");
}
__device__ __forceinline__ void ldg16B_sc(const void* p, uint32x4& a) {
    asm volatile(
        "global_load_dwordx4 %0, %1, off sc0 sc1\n\t"
        "s_waitcnt vmcnt(0)"
        : "=&v"(a)
        : "v"(p)
        : "memory");
}

__device__ __forceinline__ double mkD(unsigned lo, unsigned hi) {
    return __longlong_as_double(((ull)hi << 32) | lo);
}

__device__ __forceinline__ float softplus_f(float x) {   // bce for t=0
    return fmaxf(x, 0.0f) + log1pf(expf(-fabsf(x)));
}

__device__ __forceinline__ int bin_of_x(float x) {
    int b = (int)((x - XC) * ((float)HBINS / XRANGE));
    return max(0, min(HBINS - 1, b));
}

__device__ __forceinline__ float smooth_l1_4(float4 a, float4 b) {
    float s = 0.0f, d, ad;
    d = a.x - b.x; ad = fabsf(d); s += (ad < 1.0f) ? 0.5f * d * d : ad - 0.5f;
    d = a.y - b.y; ad = fabsf(d); s += (ad < 1.0f) ? 0.5f * d * d : ad - 0.5f;
    d = a.z - b.z; ad = fabsf(d); s += (ad < 1.0f) ? 0.5f * d * d : ad - 0.5f;
    d = a.w - b.w; ad = fabsf(d); s += (ad < 1.0f) ? 0.5f * d * d : ad - 0.5f;
    return s;
}

__device__ __forceinline__ double wredD(double v) {
#pragma unroll
    for (int o = 32; o > 0; o >>= 1) v += __shfl_down(v, o, 64);
    return v;
}
__device__ __forceinline__ int wredI(int v) {
#pragma unroll
    for (int o = 32; o > 0; o >>= 1) v += __shfl_down(v, o, 64);
    return v;
}

__device__ __forceinline__ int blockSumI(int v, int* sh) {
    int w = wredI(v);
    const int lane = threadIdx.x & 63, wid = threadIdx.x >> 6;
    __syncthreads();
    if (lane == 0) sh[wid] = w;
    __syncthreads();
    return sh[0] + sh[1] + sh[2] + sh[3];
}

// per-component histogram / selection macros over a uint32x4 quad
#define H1(XU, OFS) do { if (idx0 + (OFS) < cs) \
        atomicAdd(&hist[bin_of_x(__uint_as_float(XU))], 1u); } while (0)
#define H4(RV, Q) do { H1((RV).x, (Q)*4+0); H1((RV).y, (Q)*4+1); \
                       H1((RV).z, (Q)*4+2); H1((RV).w, (Q)*4+3); } while (0)
#define S1(XU, OFS) do { if (idx0 + (OFS) < cs) { \
        const float x_ = __uint_as_float(XU); const int b_ = bin_of_x(x_); \
        if (b_ > (int)J) acc += (double)softplus_f(x_); \
        else if (b_ == (int)J) { unsigned sl_ = atomicAdd(&shCj, 1u); \
            if (sl_ < CJCAP) ubuf[sl_] = x_; } } } while (0)
#define S4(RV, Q) do { S1((RV).x, (Q)*4+0); S1((RV).y, (Q)*4+1); \
                       S1((RV).z, (Q)*4+2); S1((RV).w, (Q)*4+3); } while (0)

__global__ void __launch_bounds__(256, 4)
mbl_fused(const float4* __restrict__ loc4, const float* __restrict__ conf,
          const float4* __restrict__ loct4, const int* __restrict__ conft,
          unsigned char* __restrict__ ws, float* __restrict__ out)
{
    __shared__ unsigned hist[HBINS];     // 16 KB (Phase B)
    __shared__ float ubuf[CJCAP];        // 4 KB  (Phase B)
    __shared__ unsigned wtot[4], wsuf[4], sccS[BPR];
    __shared__ double wrD[8], wrC[4];
    __shared__ int shI[4], shN[4], shK[4];
    __shared__ unsigned shJ, shRemJ, shNP, shT, shCj, shFB;
    __shared__ int shLast;

    const int block = blockIdx.x;
    const int row = block >> 4;          // BPR = 16
    const int base = block * CHUNK;
    const int lane = threadIdx.x & 63, wid = threadIdx.x >> 6;

    // ===================== Phase A: per-chunk pass (R9-proven) =====================
    {
        const float4* c4 = (const float4*)(conf + base);
        const int4*   t4 = (const int4*)(conft + base);

        float4 xv[4]; int4 tv[4];
#pragma unroll
        for (int it = 0; it < 4; it++) {
            const int g = threadIdx.x + it * 256;
            xv[it] = c4[g];
            tv[it] = t4[g];
        }

        double bcp = 0.0, sl1 = 0.0;
        unsigned cntc = 0, cntp = 0;
#pragma unroll
        for (int it = 0; it < 4; it++) {
#pragma unroll
            for (int c = 0; c < 4; c++) {
                float x = (c == 0) ? xv[it].x : (c == 1) ? xv[it].y : (c == 2) ? xv[it].z : xv[it].w;
                int   t = (c == 0) ? tv[it].x : (c == 1) ? tv[it].y : (c == 2) ? tv[it].z : tv[it].w;
                if (t > 0) {
                    cntp++;
                    bcp += (double)(softplus_f(x) - x);
                    const int e = base + (threadIdx.x + it * 256) * 4 + c;
                    sl1 += (double)smooth_l1_4(loc4[e], loct4[e]);
                } else if (x >= XC) cntc++;
            }
        }

        // prefix-compact candidate offsets
        unsigned incl = cntc;
#pragma unroll
        for (int o = 1; o < 64; o <<= 1) {
            unsigned v = __shfl_up(incl, o, 64);
            if (lane >= o) incl += v;
        }
        unsigned excl = incl - cntc;
        if (lane == 63) wtot[wid] = incl;
        __syncthreads();
        unsigned wbase = 0;
        for (int w = 0; w < wid; w++) wbase += wtot[w];
        const unsigned totc = wtot[0] + wtot[1] + wtot[2] + wtot[3];
        unsigned offc = excl + wbase;

        // publish candidates write-through (sc0 sc1): at L3, no dirty L2 lines
        float* seg = (float*)(ws + OFF_CAND) + (size_t)block * CHUNK;
#pragma unroll
        for (int it = 0; it < 4; it++) {
#pragma unroll
            for (int c = 0; c < 4; c++) {
                float x = (c == 0) ? xv[it].x : (c == 1) ? xv[it].y : (c == 2) ? xv[it].z : xv[it].w;
                int   t = (c == 0) ? tv[it].x : (c == 1) ? tv[it].y : (c == 2) ? tv[it].z : tv[it].w;
                if (t <= 0 && x >= XC) stgF(seg + offc++, x);
            }
        }

        double s1 = wredD(sl1), s2 = wredD(bcp);
        int tp = wredI((int)cntp);
        if (lane == 0) { wrD[wid] = s1; wrD[4 + wid] = s2; shN[wid] = tp; }
        __syncthreads();
        if (threadIdx.x == 0) {
            stgD((double*)(ws + OFF_SL1P) + block, wrD[0] + wrD[1] + wrD[2] + wrD[3]);
            stgD((double*)(ws + OFF_BCEP) + block, wrD[4] + wrD[5] + wrD[6] + wrD[7]);
            stgU((unsigned*)(ws + OFF_NP) + block, (unsigned)(shN[0] + shN[1] + shN[2] + shN[3]));
            stgU((unsigned*)(ws + OFF_CC) + block, totc);
        }
    }

    // ---- row-last election (barrier drains vmcnt -> sc1 data at L3 first)
    __syncthreads();
    if (threadIdx.x == 0) {
        unsigned old = __hip_atomic_fetch_add(
            (unsigned*)(ws + OFF_CNT) + row, 1u,
            __ATOMIC_RELAXED, __HIP_MEMORY_SCOPE_AGENT);
        shLast = (old == BPR - 1) ? 1 : 0;
    }
    __syncthreads();
    if (!shLast) return;

    // ===================== Phase B: row exact top-k (64 concurrent blocks) =====================
    {
        const unsigned* ccp = (const unsigned*)(ws + OFF_CC) + row * BPR;
        const unsigned* npp = (const unsigned*)(ws + OFF_NP) + row * BPR;
        if (wid == 0) {
            unsigned c = (lane < BPR) ? ldgU(ccp + lane) : 0u;  // parallel, 1 round
            unsigned p = (lane < BPR) ? ldgU(npp + lane) : 0u;
            if (lane < BPR) sccS[lane] = c;
            unsigned ctot = c, ptot = p;
#pragma unroll
            for (int o = 1; o < BPR; o <<= 1) {
                ctot += __shfl_down(ctot, o, 64);
                ptot += __shfl_down(ptot, o, 64);
            }
            ull ov = __ballot(lane < BPR && c > RCAP);
            if (lane == 0) {
                shT = ctot; shNP = ptot;
                shFB = (ov != 0ull) ? 1u : 0u;
                shCj = 0;
            }
        }
        __syncthreads();
    }

    const int np = (int)shNP;
    long long k = (long long)np * NEGPOS;
    if (k > D_) k = D_;
    long long negs = (long long)D_ - np;
    if (k > negs) k = negs;
    if (threadIdx.x == 0) stgI((int*)(ws + OFF_KSEL) + row, (int)k);

    bool done = false;
    if (k <= 0) {
        if (threadIdx.x == 0) stgD((double*)(ws + OFF_NEGSUM) + row, 0.0);
        done = true;
    }
    bool fb = !done && (shFB || (long long)shT < k);

    if (!done && !fb) {
        const int s = threadIdx.x >> 4, li = threadIdx.x & 15;
        const unsigned cs = sccS[s];
        const unsigned idx0 = (unsigned)li * (RQ * 4);
        const float* cand = (const float*)(ws + OFF_CAND);
        const unsigned char* segp =
            (const unsigned char*)(cand + (size_t)(row * BPR + s) * CHUNK)
            + (size_t)li * (RQ * 16);

        // whole row's candidates -> registers in one batched round
        uint32x4 r0, r1, r2, r3, r4, r5, r6, r7, r8, r9;
        ldg160B_sc(segp, r0, r1, r2, r3, r4, r5, r6, r7, r8, r9);

        for (int i = threadIdx.x; i < HBINS; i += 256) hist[i] = 0;
        __syncthreads();
        H4(r0, 0); H4(r1, 1); H4(r2, 2); H4(r3, 3); H4(r4, 4);
        H4(r5, 5); H4(r6, 6); H4(r7, 7); H4(r8, 8); H4(r9, 9);
        __syncthreads();

        // parallel suffix scan over 4096 bins -> threshold bin J, remJ
        unsigned s16 = 0;
        const int b0i = threadIdx.x * 16;
#pragma unroll
        for (int j = 0; j < 16; j++) s16 += hist[b0i + j];
        unsigned suf = s16;
#pragma unroll
        for (int o = 1; o < 64; o <<= 1) {
            unsigned v = __shfl_down(suf, o, 64);
            if (lane + o < 64) suf += v;
        }
        if (lane == 0) wsuf[wid] = suf;
        __syncthreads();
        unsigned addw = 0;
        for (int w = wid + 1; w < 4; w++) addw += wsuf[w];
        suf += addw;
        const unsigned sufx = suf - s16;
        if ((long long)sufx < k && (long long)suf >= k) {
            long long cum = sufx;
            for (int j = 15; j >= 0; j--) {
                cum += hist[b0i + j];
                if (cum >= k) {
                    shJ = (unsigned)(b0i + j);
                    shRemJ = (unsigned)(k - (cum - (long long)hist[b0i + j]));
                    break;
                }
            }
        }
        __syncthreads();
        const unsigned J = shJ, remJ = shRemJ;

        // selection pass over REGISTERS: softplus sum of bins > J + bin-J gather
        double acc = 0.0;
        S4(r0, 0); S4(r1, 1); S4(r2, 2); S4(r3, 3); S4(r4, 4);
        S4(r5, 5); S4(r6, 6); S4(r7, 7); S4(r8, 8); S4(r9, 9);
        __syncthreads();
        const unsigned cj = shCj;

        if (cj <= CJCAP) {
            // exact rank-select inside bin J (ties are equal values -> sum
            // independent of nondeterministic ubuf slot order)
            for (unsigned i = threadIdx.x; i < cj; i += 256) {
                const float xi = ubuf[i];
                unsigned r = 0;
                for (unsigned l = 0; l < cj; l++) {
                    const float xl = ubuf[l];
                    r += (xl > xi || (xl == xi && l < i)) ? 1u : 0u;
                }
                if (r < remJ) acc += (double)softplus_f(xi);
            }
            double t = wredD(acc);
            if (lane == 0) wrD[wid] = t;
            __syncthreads();
            if (threadIdx.x == 0)
                stgD((double*)(ws + OFF_NEGSUM) + row,
                     wrD[0] + wrD[1] + wrD[2] + wrD[3]);
            done = true;
        } else fb = true;   // pathological mass-tie
    }

    if (!done && fb) {
        // exact uint-bisection over the full row (inputs: plain cached loads)
        const float* rowc = conf + row * D_;
        const int*   rowt = conft + row * D_;
        unsigned lo = 0u, hi = 0xFFFFFFFFu;
        for (int it = 0; it < 32; it++) {
            const unsigned mid = lo + ((hi - lo) >> 1);
            unsigned um = (mid & 0x80000000u) ? (mid & 0x7FFFFFFFu) : ~mid;
            float fm = __uint_as_float(um);
            int c = 0;
            for (int i = threadIdx.x; i < D_; i += 256)
                if (rowt[i] <= 0 && rowc[i] > fm) c++;
            const int tot = blockSumI(c, shI);
            if ((long long)tot >= k) lo = mid; else hi = mid;
        }
        unsigned uT = (hi & 0x80000000u) ? (hi & 0x7FFFFFFFu) : ~hi;
        float xT = __uint_as_float(uT);
        int c = 0;
        double acc = 0.0;
        for (int i = threadIdx.x; i < D_; i += 256) {
            if (rowt[i] <= 0) {
                float x = rowc[i];
                if (x > xT) { c++; acc += (double)softplus_f(x); }
            }
        }
        int rem = (int)(k - (long long)blockSumI(c, shI));
        double t = wredD(acc);
        if (lane == 0) wrD[wid] = t;
        __syncthreads();
        if (threadIdx.x == 0)
            stgD((double*)(ws + OFF_NEGSUM) + row,
                 wrD[0] + wrD[1] + wrD[2] + wrD[3] +
                 (double)rem * (double)softplus_f(xT));
    }

    // ---- done-row election
    __syncthreads();
    if (threadIdx.x == 0) {
        unsigned old = __hip_atomic_fetch_add(
            (unsigned*)(ws + OFF_CNT) + B_, 1u,
            __ATOMIC_RELAXED, __HIP_MEMORY_SCOPE_AGENT);
        shLast = (old == B_ - 1) ? 1 : 0;
    }
    __syncthreads();
    if (!shLast) return;

    // ===================== Phase C: final reduce (batched loads) =====================
    {
        uint32x4 pa, pb, qa, qb, na;
        ldg32B_sc(ws + OFF_SL1P + (size_t)threadIdx.x * 32, pa, pb);   // 4 doubles
        ldg32B_sc(ws + OFF_BCEP + (size_t)threadIdx.x * 32, qa, qb);   // 4 doubles
        ldg16B_sc(ws + OFF_NP + (size_t)threadIdx.x * 16, na);         // 4 u32
        double a  = mkD(pa.x, pa.y) + mkD(pa.z, pa.w) + mkD(pb.x, pb.y) + mkD(pb.z, pb.w);
        double b2 = mkD(qa.x, qa.y) + mkD(qa.z, qa.w) + mkD(qb.x, qb.y) + mkD(qb.z, qb.w);
        int nn = (int)(na.x + na.y + na.z + na.w);
        double c2 = 0.0; int kk = 0;
        if (threadIdx.x < 16) {
            uint32x4 ca, cb, ka;
            ldg32B_sc(ws + OFF_NEGSUM + (size_t)threadIdx.x * 32, ca, cb);
            ldg16B_sc(ws + OFF_KSEL + (size_t)threadIdx.x * 16, ka);
            c2 = mkD(ca.x, ca.y) + mkD(ca.z, ca.w) + mkD(cb.x, cb.y) + mkD(cb.z, cb.w);
            kk = (int)ka.x + (int)ka.y + (int)ka.z + (int)ka.w;
        }

        double ra = wredD(a), rb = wredD(b2), rc = wredD(c2);
        int rn = wredI(nn), rk = wredI(kk);
        if (lane == 0) { wrD[wid] = ra; wrD[4 + wid] = rb; wrC[wid] = rc; shN[wid] = rn; shK[wid] = rk; }
        __syncthreads();
        if (threadIdx.x == 0) {
            double SL1 = wrD[0] + wrD[1] + wrD[2] + wrD[3];
            double BCE = wrD[4] + wrD[5] + wrD[6] + wrD[7];
            double NSUM = wrC[0] + wrC[1] + wrC[2] + wrC[3];
            double Np = (double)(shN[0] + shN[1] + shN[2] + shN[3]);
            double Kt = (double)(shK[0] + shK[1] + shK[2] + shK[3]);
            double out0 = (Np > 0.0) ? (SL1 / (4.0 * Np)) / Np : 0.0;
            double denom = Np + Kt;
            double out1 = (Np > 0.0 && denom > 0.0) ? ((BCE + NSUM) / denom) / Np : 0.0;
            out[0] = (float)out0;
            out[1] = (float)out1;
        }
    }
}

extern "C" void kernel_launch(void* const* d_in, const int* in_sizes, int n_in,
                              void* d_out, int out_size, void* d_ws, size_t ws_size,
                              hipStream_t stream)
{
    const float4* loc4  = (const float4*)d_in[0];   // (B,D,4) f32
    const float*  conf  = (const float*)d_in[1];    // (B,D,1) f32
    const float4* loct4 = (const float4*)d_in[2];   // (B,D,4) f32
    const int*    conft = (const int*)d_in[3];      // (B,D)   i32
    unsigned char* ws = (unsigned char*)d_ws;
    float* out = (float*)d_out;

    // zero the 65 election counters (ws is poisoned each iteration)
    hipMemsetAsync(ws + OFF_CNT, 0, (B_ + 1) * sizeof(unsigned), stream);
    mbl_fused<<<dim3(NBLK), dim3(256), 0, stream>>>(loc4, conf, loct4, conft, ws, out);
}

// Round 6
// 186.688 us; speedup vs baseline: 1.2444x; 1.2203x over previous
//
#include <hip/hip_runtime.h>
#include <stdint.h>

// MultiBoxLoss: B=64 rows, D=65536 anchors, ~2% positives.
// R13: keep only measured-good components.
//  - Phase A: R9 verbatim (LDS compaction + COALESCED sc1 publish, ~15us,
//    WRITE 1.88MB). R12's scattered per-thread sc1 stores amplified writes
//    6x (11.6MB) and slowed store issue -> reverted.
//  - Phase B: R9's structure, but the candidate passes stream with 4-deep
//    batched asm loads (ldg64B = 4 x dwordx4, ONE vmcnt) instead of R9's
//    one-at-a-time __hip_atomic_load (27 serialized ~0.9us L3 trips x2
//    passes = its 50us tail) and instead of R12's monolithic 40-VGPR
//    register staging (register pathology, 120us tail). ~2 iterations/pass,
//    1024 loads in flight per block -> ~5us total.
//  - Phase C: R12's batched loads (correct + fast there).
// Elections: RELAXED agent-scope RMW (R9-proven: no cache-wide wbl2/inv);
// pre-election __syncthreads drains vmcnt so sc1 data is at L3 before the
// counter RMW lands there. memset/iter: 260B election counters only.

#define B_ 64
#define D_ 65536
#define NEGPOS 3
#define BPR 16                 // blocks per row
#define NBLK (B_ * BPR)        // 1024
#define CHUNK (D_ / BPR)       // 4096 elements per block
#define XC 1.25f               // candidate cutoff (P(x>=XC)~10.6% per row)
#define HBINS 4096             // histogram bins over x in [XC, XC+XRANGE)
#define XRANGE 5.0f
#define CJCAP 1024             // bin-J gather capacity (expect ~9)

typedef unsigned long long ull;
typedef unsigned uint32x4 __attribute__((ext_vector_type(4)));  // legal "v" type

// ---------------- ws layout (bytes) ----------------
#define OFF_SL1P   0           // double[NBLK]
#define OFF_BCEP   8192        // double[NBLK]
#define OFF_NP     16384       // u32[NBLK]
#define OFF_CC     20480       // u32[NBLK]
#define OFF_NEGSUM 24576       // double[64]
#define OFF_KSEL   25088       // int[64]
#define OFF_CNT    25344       // u32 rowcnt[64] + u32 done  [zeroed per iter]
#define OFF_CAND   32768       // float[NBLK][CHUNK] = 16 MiB (ws >= 36MiB per R11)

// ---- agent-coherent (sc0 sc1) relaxed ops: per-instruction coherence,
// no cache-wide wbl2/inv (R9-proven correct+fast on this HW).
__device__ __forceinline__ void stgF(float* p, float v) {
    __hip_atomic_store(p, v, __ATOMIC_RELAXED, __HIP_MEMORY_SCOPE_AGENT);
}
__device__ __forceinline__ void stgU(unsigned* p, unsigned v) {
    __hip_atomic_store(p, v, __ATOMIC_RELAXED, __HIP_MEMORY_SCOPE_AGENT);
}
__device__ __forceinline__ void stgI(int* p, int v) {
    __hip_atomic_store(p, v, __ATOMIC_RELAXED, __HIP_MEMORY_SCOPE_AGENT);
}
__device__ __forceinline__ void stgD(double* p, double v) {
    __hip_atomic_store(p, v, __ATOMIC_RELAXED, __HIP_MEMORY_SCOPE_AGENT);
}
__device__ __forceinline__ unsigned ldgU(const unsigned* p) {
    return __hip_atomic_load(p, __ATOMIC_RELAXED, __HIP_MEMORY_SCOPE_AGENT);
}

// ---- batched L2-bypass loads: N dwordx4 then ONE waitcnt inside a single
// asm block (early-clobber outputs; consumers read outputs -> data dep).
__device__ __forceinline__ void ldg64B_sc(const void* p,
                                          uint32x4& a, uint32x4& b,
                                          uint32x4& c, uint32x4& d) {
    asm volatile(
        "global_load_dwordx4 %0, %4, off sc0 sc1\n\t"
        "global_load_dwordx4 %1, %4, off offset:16 sc0 sc1\n\t"
        "global_load_dwordx4 %2, %4, off offset:32 sc0 sc1\n\t"
        "global_load_dwordx4 %3, %4, off offset:48 sc0 sc1\n\t"
        "s_waitcnt vmcnt(0)"
        : "=&v"(a), "=&v"(b), "=&v"(c), "=&v"(d)
        : "v"(p)
        : "memory");
}
__device__ __forceinline__ void ldg32B_sc(const void* p, uint32x4& a, uint32x4& b) {
    asm volatile(
        "global_load_dwordx4 %0, %2, off sc0 sc1\n\t"
        "global_load_dwordx4 %1, %2, off offset:16 sc0 sc1\n\t"
        "s_waitcnt vmcnt(0)"
        : "=&v"(a), "=&v"(b)
        : "v"(p)
        : "memory");
}
__device__ __forceinline__ void ldg16B_sc(const void* p, uint32x4& a) {
    asm volatile(
        "global_load_dwordx4 %0, %1, off sc0 sc1\n\t"
        "s_waitcnt vmcnt(0)"
        : "=&v"(a)
        : "v"(p)
        : "memory");
}

__device__ __forceinline__ double mkD(unsigned lo, unsigned hi) {
    return __longlong_as_double(((ull)hi << 32) | lo);
}

__device__ __forceinline__ float softplus_f(float x) {   // bce for t=0
    return fmaxf(x, 0.0f) + log1pf(expf(-fabsf(x)));
}

__device__ __forceinline__ int bin_of_x(float x) {
    int b = (int)((x - XC) * ((float)HBINS / XRANGE));
    return max(0, min(HBINS - 1, b));
}

__device__ __forceinline__ float smooth_l1_4(float4 a, float4 b) {
    float s = 0.0f, d, ad;
    d = a.x - b.x; ad = fabsf(d); s += (ad < 1.0f) ? 0.5f * d * d : ad - 0.5f;
    d = a.y - b.y; ad = fabsf(d); s += (ad < 1.0f) ? 0.5f * d * d : ad - 0.5f;
    d = a.z - b.z; ad = fabsf(d); s += (ad < 1.0f) ? 0.5f * d * d : ad - 0.5f;
    d = a.w - b.w; ad = fabsf(d); s += (ad < 1.0f) ? 0.5f * d * d : ad - 0.5f;
    return s;
}

__device__ __forceinline__ double wredD(double v) {
#pragma unroll
    for (int o = 32; o > 0; o >>= 1) v += __shfl_down(v, o, 64);
    return v;
}
__device__ __forceinline__ int wredI(int v) {
#pragma unroll
    for (int o = 32; o > 0; o >>= 1) v += __shfl_down(v, o, 64);
    return v;
}

__device__ __forceinline__ int blockSumI(int v, int* sh) {
    int w = wredI(v);
    const int lane = threadIdx.x & 63, wid = threadIdx.x >> 6;
    __syncthreads();
    if (lane == 0) sh[wid] = w;
    __syncthreads();
    return sh[0] + sh[1] + sh[2] + sh[3];
}

// guarded per-component histogram / selection over a uint32x4 quad
#define HG(Q, OFS) do { \
    if (i0 + (OFS) + 0 < cs) atomicAdd(&hist[bin_of_x(__uint_as_float((Q).x))], 1u); \
    if (i0 + (OFS) + 1 < cs) atomicAdd(&hist[bin_of_x(__uint_as_float((Q).y))], 1u); \
    if (i0 + (OFS) + 2 < cs) atomicAdd(&hist[bin_of_x(__uint_as_float((Q).z))], 1u); \
    if (i0 + (OFS) + 3 < cs) atomicAdd(&hist[bin_of_x(__uint_as_float((Q).w))], 1u); } while (0)
#define SG1(XU, OFS) do { if (i0 + (OFS) < cs) { \
        const float x_ = __uint_as_float(XU); const int b_ = bin_of_x(x_); \
        if (b_ > (int)J) acc += (double)softplus_f(x_); \
        else if (b_ == (int)J) { unsigned sl_ = atomicAdd(&shCj, 1u); \
            if (sl_ < CJCAP) ubuf[sl_] = x_; } } } while (0)
#define SG(Q, OFS) do { SG1((Q).x, (OFS)+0); SG1((Q).y, (OFS)+1); \
                        SG1((Q).z, (OFS)+2); SG1((Q).w, (OFS)+3); } while (0)

__global__ void __launch_bounds__(256)
mbl_fused(const float4* __restrict__ loc4, const float* __restrict__ conf,
          const float4* __restrict__ loct4, const int* __restrict__ conft,
          unsigned char* __restrict__ ws, float* __restrict__ out)
{
    // Phase A needs lcand+lpos (24KB); Phase B needs hist+ubuf (20KB).
    // Never live at the same time -> union keeps LDS at ~25KB (6 blk/CU).
    __shared__ union {
        struct { float lcand[CHUNK]; unsigned short lpos[CHUNK]; } a;
        struct { unsigned hist[HBINS]; float ubuf[CJCAP]; } b;
    } u;
    __shared__ unsigned wtot[4], wsuf[4], sccS[BPR];
    __shared__ double wrD[8], wrC[4];
    __shared__ int shI[4], shN[4], shK[4];
    __shared__ unsigned shJ, shRemJ, shNP, shT, shCj;
    __shared__ int shLast;

    const int block = blockIdx.x;
    const int row = block >> 4;          // BPR = 16
    const int base = block * CHUNK;
    const int lane = threadIdx.x & 63, wid = threadIdx.x >> 6;

    // ===================== Phase A: per-chunk pass (R9 verbatim) =====================
    {
        const float4* c4 = (const float4*)(conf + base);
        const int4*   t4 = (const int4*)(conft + base);

        float4 xv[4]; int4 tv[4];
#pragma unroll
        for (int it = 0; it < 4; it++) {
            const int g = threadIdx.x + it * 256;
            xv[it] = c4[g];
            tv[it] = t4[g];
        }

        double bcp = 0.0;
        unsigned cntc = 0, cntp = 0;
#pragma unroll
        for (int it = 0; it < 4; it++) {
#pragma unroll
            for (int c = 0; c < 4; c++) {
                float x = (c == 0) ? xv[it].x : (c == 1) ? xv[it].y : (c == 2) ? xv[it].z : xv[it].w;
                int   t = (c == 0) ? tv[it].x : (c == 1) ? tv[it].y : (c == 2) ? tv[it].z : tv[it].w;
                if (t > 0) { cntp++; bcp += (double)(softplus_f(x) - x); }
                else if (x >= XC) cntc++;
            }
        }

        unsigned pk = (cntc << 16) | cntp;
        unsigned incl = pk;
#pragma unroll
        for (int o = 1; o < 64; o <<= 1) {
            unsigned v = __shfl_up(incl, o, 64);
            if (lane >= o) incl += v;
        }
        unsigned excl = incl - pk;
        if (lane == 63) wtot[wid] = incl;
        __syncthreads();
        unsigned wbase = 0;
        for (int w = 0; w < wid; w++) wbase += wtot[w];
        const unsigned tot = wtot[0] + wtot[1] + wtot[2] + wtot[3];
        const unsigned totc = tot >> 16, totp = tot & 0xFFFFu;
        unsigned offc = (excl >> 16) + (wbase >> 16);
        unsigned offp = (excl & 0xFFFFu) + (wbase & 0xFFFFu);

#pragma unroll
        for (int it = 0; it < 4; it++) {
#pragma unroll
            for (int c = 0; c < 4; c++) {
                float x = (c == 0) ? xv[it].x : (c == 1) ? xv[it].y : (c == 2) ? xv[it].z : xv[it].w;
                int   t = (c == 0) ? tv[it].x : (c == 1) ? tv[it].y : (c == 2) ? tv[it].z : tv[it].w;
                const int li = (threadIdx.x + it * 256) * 4 + c;
                if (t > 0) u.a.lpos[offp++] = (unsigned short)li;
                else if (x >= XC) u.a.lcand[offc++] = x;
            }
        }
        __syncthreads();

        // coalesced write-through publish (sc0 sc1): at L3, no dirty L2 lines
        float* seg = (float*)(ws + OFF_CAND) + (size_t)block * CHUNK;
        for (unsigned i = threadIdx.x; i < totc; i += 256) stgF(seg + i, u.a.lcand[i]);

        double sl1 = 0.0;
        for (unsigned i = threadIdx.x; i < totp; i += 256) {
            const int e = base + (int)u.a.lpos[i];
            sl1 += (double)smooth_l1_4(loc4[e], loct4[e]);
        }

        double s1 = wredD(sl1), s2 = wredD(bcp);
        if (lane == 0) { wrD[wid] = s1; wrD[4 + wid] = s2; }
        __syncthreads();
        if (threadIdx.x == 0) {
            stgD((double*)(ws + OFF_SL1P) + block, wrD[0] + wrD[1] + wrD[2] + wrD[3]);
            stgD((double*)(ws + OFF_BCEP) + block, wrD[4] + wrD[5] + wrD[6] + wrD[7]);
            stgU((unsigned*)(ws + OFF_NP) + block, totp);
            stgU((unsigned*)(ws + OFF_CC) + block, totc);
        }
    }

    // ---- row-last election (barrier drains vmcnt -> sc1 data at L3 first)
    __syncthreads();
    if (threadIdx.x == 0) {
        unsigned old = __hip_atomic_fetch_add(
            (unsigned*)(ws + OFF_CNT) + row, 1u,
            __ATOMIC_RELAXED, __HIP_MEMORY_SCOPE_AGENT);
        shLast = (old == BPR - 1) ? 1 : 0;
    }
    __syncthreads();
    if (!shLast) return;

    // ===================== Phase B: row exact top-k (64 concurrent blocks) =====================
    {
        const unsigned* ccp = (const unsigned*)(ws + OFF_CC) + row * BPR;
        const unsigned* npp = (const unsigned*)(ws + OFF_NP) + row * BPR;
        if (wid == 0) {
            unsigned c = (lane < BPR) ? ldgU(ccp + lane) : 0u;   // parallel lanes
            unsigned p = (lane < BPR) ? ldgU(npp + lane) : 0u;
            if (lane < BPR) sccS[lane] = c;
            unsigned ct = c, pt = p;
#pragma unroll
            for (int o = 1; o < BPR; o <<= 1) {
                ct += __shfl_down(ct, o, 64);
                pt += __shfl_down(pt, o, 64);
            }
            if (lane == 0) { shT = ct; shNP = pt; shCj = 0; }
        }
        __syncthreads();
    }

    const int np = (int)shNP;
    const unsigned n = shT;
    long long k = (long long)np * NEGPOS;
    if (k > D_) k = D_;
    long long negs = (long long)D_ - np;
    if (k > negs) k = negs;
    if (threadIdx.x == 0) stgI((int*)(ws + OFF_KSEL) + row, (int)k);

    bool done = false, fb = false;
    if (k <= 0) {
        if (threadIdx.x == 0) stgD((double*)(ws + OFF_NEGSUM) + row, 0.0);
        done = true;
    } else if ((long long)n < k) {
        fb = true;                        // not enough candidates above XC
    }

    if (!done && !fb) {
        unsigned* hist = u.b.hist;
        float* ubuf = u.b.ubuf;
        const int s = threadIdx.x >> 4, li = threadIdx.x & 15;
        const unsigned cs = sccS[s];
        const float* segf = (const float*)(ws + OFF_CAND) + (size_t)(row * BPR + s) * CHUNK;

        for (int i = threadIdx.x; i < HBINS; i += 256) hist[i] = 0;
        __syncthreads();

        // pass 1: streamed batched loads -> LDS histogram (~2 iters/thread)
        for (unsigned i0 = (unsigned)li * 16u; i0 < cs; i0 += 256u) {
            uint32x4 q0, q1, q2, q3;
            ldg64B_sc(segf + i0, q0, q1, q2, q3);
            HG(q0, 0); HG(q1, 4); HG(q2, 8); HG(q3, 12);
        }
        __syncthreads();

        // parallel suffix scan over 4096 bins -> threshold bin J, remJ
        unsigned s16 = 0;
        const int b0i = threadIdx.x * 16;
#pragma unroll
        for (int j = 0; j < 16; j++) s16 += hist[b0i + j];
        unsigned suf = s16;
#pragma unroll
        for (int o = 1; o < 64; o <<= 1) {
            unsigned v = __shfl_down(suf, o, 64);
            if (lane + o < 64) suf += v;
        }
        if (lane == 0) wsuf[wid] = suf;
        __syncthreads();
        unsigned addw = 0;
        for (int w = wid + 1; w < 4; w++) addw += wsuf[w];
        suf += addw;                          // inclusive suffix over all 256
        const unsigned sufx = suf - s16;      // bins strictly above my chunk
        if ((long long)sufx < k && (long long)suf >= k) {
            long long cum = sufx;
            for (int j = 15; j >= 0; j--) {
                cum += hist[b0i + j];
                if (cum >= k) {
                    shJ = (unsigned)(b0i + j);
                    shRemJ = (unsigned)(k - (cum - (long long)hist[b0i + j]));
                    break;
                }
            }
        }
        __syncthreads();
        const unsigned J = shJ, remJ = shRemJ;

        // pass 2: streamed again; sum softplus of bins > J, gather bin-J
        double acc = 0.0;
        for (unsigned i0 = (unsigned)li * 16u; i0 < cs; i0 += 256u) {
            uint32x4 q0, q1, q2, q3;
            ldg64B_sc(segf + i0, q0, q1, q2, q3);
            SG(q0, 0); SG(q1, 4); SG(q2, 8); SG(q3, 12);
        }
        __syncthreads();
        const unsigned cj = shCj;

        if (cj <= CJCAP) {
            // exact rank-select inside bin J (ties equal values -> selected
            // multiset independent of nondeterministic slot order)
            for (unsigned i = threadIdx.x; i < cj; i += 256) {
                const float xi = ubuf[i];
                unsigned r = 0;
                for (unsigned l = 0; l < cj; l++) {
                    const float xl = ubuf[l];
                    r += (xl > xi || (xl == xi && l < i)) ? 1u : 0u;
                }
                if (r < remJ) acc += (double)softplus_f(xi);
            }
            double t = wredD(acc);
            if (lane == 0) wrD[wid] = t;
            __syncthreads();
            if (threadIdx.x == 0)
                stgD((double*)(ws + OFF_NEGSUM) + row,
                     wrD[0] + wrD[1] + wrD[2] + wrD[3]);
            done = true;
        } else fb = true;   // pathological mass-tie
    }

    if (!done && fb) {
        // exact uint-bisection over the full row (inputs: plain cached loads)
        const float* rowc = conf + row * D_;
        const int*   rowt = conft + row * D_;
        unsigned lo = 0u, hi = 0xFFFFFFFFu;
        for (int it = 0; it < 32; it++) {
            const unsigned mid = lo + ((hi - lo) >> 1);
            unsigned um = (mid & 0x80000000u) ? (mid & 0x7FFFFFFFu) : ~mid;
            float fm = __uint_as_float(um);
            int c = 0;
            for (int i = threadIdx.x; i < D_; i += 256)
                if (rowt[i] <= 0 && rowc[i] > fm) c++;
            const int tot = blockSumI(c, shI);
            if ((long long)tot >= k) lo = mid; else hi = mid;
        }
        unsigned uT = (hi & 0x80000000u) ? (hi & 0x7FFFFFFFu) : ~hi;
        float xT = __uint_as_float(uT);
        int c = 0;
        double acc = 0.0;
        for (int i = threadIdx.x; i < D_; i += 256) {
            if (rowt[i] <= 0) {
                float x = rowc[i];
                if (x > xT) { c++; acc += (double)softplus_f(x); }
            }
        }
        int rem = (int)(k - (long long)blockSumI(c, shI));
        double t = wredD(acc);
        if (lane == 0) wrD[wid] = t;
        __syncthreads();
        if (threadIdx.x == 0)
            stgD((double*)(ws + OFF_NEGSUM) + row,
                 wrD[0] + wrD[1] + wrD[2] + wrD[3] +
                 (double)rem * (double)softplus_f(xT));
    }

    // ---- done-row election
    __syncthreads();
    if (threadIdx.x == 0) {
        unsigned old = __hip_atomic_fetch_add(
            (unsigned*)(ws + OFF_CNT) + B_, 1u,
            __ATOMIC_RELAXED, __HIP_MEMORY_SCOPE_AGENT);
        shLast = (old == B_ - 1) ? 1 : 0;
    }
    __syncthreads();
    if (!shLast) return;

    // ===================== Phase C: final reduce (batched loads, R12-proven) =====================
    {
        uint32x4 pa, pb, qa, qb, na;
        ldg32B_sc(ws + OFF_SL1P + (size_t)threadIdx.x * 32, pa, pb);   // 4 doubles
        ldg32B_sc(ws + OFF_BCEP + (size_t)threadIdx.x * 32, qa, qb);   // 4 doubles
        ldg16B_sc(ws + OFF_NP + (size_t)threadIdx.x * 16, na);         // 4 u32
        double a  = mkD(pa.x, pa.y) + mkD(pa.z, pa.w) + mkD(pb.x, pb.y) + mkD(pb.z, pb.w);
        double b2 = mkD(qa.x, qa.y) + mkD(qa.z, qa.w) + mkD(qb.x, qb.y) + mkD(qb.z, qb.w);
        int nn = (int)(na.x + na.y + na.z + na.w);
        double c2 = 0.0; int kk = 0;
        if (threadIdx.x < 16) {
            uint32x4 ca, cb, ka;
            ldg32B_sc(ws + OFF_NEGSUM + (size_t)threadIdx.x * 32, ca, cb);
            ldg16B_sc(ws + OFF_KSEL + (size_t)threadIdx.x * 16, ka);
            c2 = mkD(ca.x, ca.y) + mkD(ca.z, ca.w) + mkD(cb.x, cb.y) + mkD(cb.z, cb.w);
            kk = (int)ka.x + (int)ka.y + (int)ka.z + (int)ka.w;
        }

        double ra = wredD(a), rb = wredD(b2), rc = wredD(c2);
        int rn = wredI(nn), rk = wredI(kk);
        if (lane == 0) { wrD[wid] = ra; wrD[4 + wid] = rb; wrC[wid] = rc; shN[wid] = rn; shK[wid] = rk; }
        __syncthreads();
        if (threadIdx.x == 0) {
            double SL1 = wrD[0] + wrD[1] + wrD[2] + wrD[3];
            double BCE = wrD[4] + wrD[5] + wrD[6] + wrD[7];
            double NSUM = wrC[0] + wrC[1] + wrC[2] + wrC[3];
            double Np = (double)(shN[0] + shN[1] + shN[2] + shN[3]);
            double Kt = (double)(shK[0] + shK[1] + shK[2] + shK[3]);
            double out0 = (Np > 0.0) ? (SL1 / (4.0 * Np)) / Np : 0.0;
            double denom = Np + Kt;
            double out1 = (Np > 0.0 && denom > 0.0) ? ((BCE + NSUM) / denom) / Np : 0.0;
            out[0] = (float)out0;
            out[1] = (float)out1;
        }
    }
}

extern "C" void kernel_launch(void* const* d_in, const int* in_sizes, int n_in,
                              void* d_out, int out_size, void* d_ws, size_t ws_size,
                              hipStream_t stream)
{
    const float4* loc4  = (const float4*)d_in[0];   // (B,D,4) f32
    const float*  conf  = (const float*)d_in[1];    // (B,D,1) f32
    const float4* loct4 = (const float4*)d_in[2];   // (B,D,4) f32
    const int*    conft = (const int*)d_in[3];      // (B,D)   i32
    unsigned char* ws = (unsigned char*)d_ws;
    float* out = (float*)d_out;

    // zero the 65 election counters (ws is poisoned each iteration)
    hipMemsetAsync(ws + OFF_CNT, 0, (B_ + 1) * sizeof(unsigned), stream);
    mbl_fused<<<dim3(NBLK), dim3(256), 0, stream>>>(loc4, conf, loct4, conft, ws, out);
}

// Round 8
// 174.678 us; speedup vs baseline: 1.3300x; 1.0688x over previous
//
#include <hip/hip_runtime.h>
#include <stdint.h>

// MultiBoxLoss: B=64 rows, D=65536 anchors, ~2% positives.
// R15 = R14 de-risked: two consecutive container failures (R10: inline-asm
// suspect; R14: NO exotic constructs at all -> infra flake likely). This
// submission is the maximally-proven shell: R7's three-kernel structure
// (passed at 175.5us), ZERO __hip_atomic, ZERO inline asm, ZERO elections,
// ZERO memset (k1 writes all 1024 partial slots, k2 writes all 64 row
// slots, k5 reads; kernel boundaries provide cross-XCD coherence).
// Experimental content (what R14 tested): k2 = 64-block per-row selection
// streaming the compacted candidate array with plain compiler-pipelined
// float4 loads (R7's ksel staged candidates through LDS with serial chains;
// R9/R13 showed the fused tail is NOT load latency -> this isolates what it
// IS). rocprof reports k1/k2/k5 separately next round:
//   - k2 VALUBusy high  -> softplus/binning VALU-bound
//   - k2 FETCH high     -> candidate re-fetch from HBM (expected L2/L3-hit)
//   - k2 LDS conflicts  -> histogram atomics
// Prediction: k1 12-16us, k2 8-15us (work model) or 40-50us (intrinsic),
// k5 2-3us.

#define B_ 64
#define D_ 65536
#define NEGPOS 3
#define BPR 16                 // k1 blocks per row
#define NBLK (B_ * BPR)        // 1024
#define CHUNK (D_ / BPR)       // 4096 elements per k1 block
#define XC 1.25f               // candidate cutoff (P(x>=XC)~10.6% per row)
#define HBINS 4096             // histogram bins over x in [XC, XC+XRANGE)
#define XRANGE 5.0f
#define CJCAP 1024             // bin-J gather capacity (expect ~9)

// ---------------- ws layout (bytes), nothing needs zeroing ----------------
#define OFF_SL1P   0           // double[NBLK]   (k1 -> k5)
#define OFF_BCEP   8192        // double[NBLK]   (k1 -> k5)
#define OFF_NP     16384       // u32[NBLK]      (k1 -> k2,k5)
#define OFF_CC     20480       // u32[NBLK]      (k1 -> k2)
#define OFF_NEGSUM 24576       // double[64]     (k2 -> k5)
#define OFF_KSEL   25088       // int[64]        (k2 -> k5)
#define OFF_CAND   32768       // float[NBLK][CHUNK] = 16 MiB (k1 -> k2)

__device__ __forceinline__ float softplus_f(float x) {   // bce for t=0
    return fmaxf(x, 0.0f) + log1pf(expf(-fabsf(x)));
}

__device__ __forceinline__ int bin_of_x(float x) {
    int b = (int)((x - XC) * ((float)HBINS / XRANGE));
    return max(0, min(HBINS - 1, b));
}

__device__ __forceinline__ float smooth_l1_4(float4 a, float4 b) {
    float s = 0.0f, d, ad;
    d = a.x - b.x; ad = fabsf(d); s += (ad < 1.0f) ? 0.5f * d * d : ad - 0.5f;
    d = a.y - b.y; ad = fabsf(d); s += (ad < 1.0f) ? 0.5f * d * d : ad - 0.5f;
    d = a.z - b.z; ad = fabsf(d); s += (ad < 1.0f) ? 0.5f * d * d : ad - 0.5f;
    d = a.w - b.w; ad = fabsf(d); s += (ad < 1.0f) ? 0.5f * d * d : ad - 0.5f;
    return s;
}

__device__ __forceinline__ double wredD(double v) {
#pragma unroll
    for (int o = 32; o > 0; o >>= 1) v += __shfl_down(v, o, 64);
    return v;
}
__device__ __forceinline__ int wredI(int v) {
#pragma unroll
    for (int o = 32; o > 0; o >>= 1) v += __shfl_down(v, o, 64);
    return v;
}

__device__ __forceinline__ int blockSumI(int v, int* sh) {
    int w = wredI(v);
    const int lane = threadIdx.x & 63, wid = threadIdx.x >> 6;
    __syncthreads();
    if (lane == 0) sh[wid] = w;
    __syncthreads();
    return sh[0] + sh[1] + sh[2] + sh[3];
}

// ===================== K1: per-chunk pass (1024 blocks, R7-proven) =====================
__global__ void __launch_bounds__(256)
mbl_k1(const float4* __restrict__ loc4, const float* __restrict__ conf,
       const float4* __restrict__ loct4, const int* __restrict__ conft,
       unsigned char* __restrict__ ws)
{
    __shared__ float lcand[CHUNK];           // 16 KB
    __shared__ unsigned short lpos[CHUNK];   // 8 KB
    __shared__ unsigned wtot[4];
    __shared__ double wrD[8];

    const int block = blockIdx.x;
    const int base = block * CHUNK;
    const int lane = threadIdx.x & 63, wid = threadIdx.x >> 6;

    const float4* c4 = (const float4*)(conf + base);
    const int4*   t4 = (const int4*)(conft + base);

    float4 xv[4]; int4 tv[4];
#pragma unroll
    for (int it = 0; it < 4; it++) {
        const int g = threadIdx.x + it * 256;
        xv[it] = c4[g];
        tv[it] = t4[g];
    }

    double bcp = 0.0;
    unsigned cntc = 0, cntp = 0;
#pragma unroll
    for (int it = 0; it < 4; it++) {
#pragma unroll
        for (int c = 0; c < 4; c++) {
            float x = (c == 0) ? xv[it].x : (c == 1) ? xv[it].y : (c == 2) ? xv[it].z : xv[it].w;
            int   t = (c == 0) ? tv[it].x : (c == 1) ? tv[it].y : (c == 2) ? tv[it].z : tv[it].w;
            if (t > 0) { cntp++; bcp += (double)(softplus_f(x) - x); }
            else if (x >= XC) cntc++;
        }
    }

    unsigned pk = (cntc << 16) | cntp;
    unsigned incl = pk;
#pragma unroll
    for (int o = 1; o < 64; o <<= 1) {
        unsigned v = __shfl_up(incl, o, 64);
        if (lane >= o) incl += v;
    }
    unsigned excl = incl - pk;
    if (lane == 63) wtot[wid] = incl;
    __syncthreads();
    unsigned wbase = 0;
    for (int w = 0; w < wid; w++) wbase += wtot[w];
    const unsigned tot = wtot[0] + wtot[1] + wtot[2] + wtot[3];
    const unsigned totc = tot >> 16, totp = tot & 0xFFFFu;
    unsigned offc = (excl >> 16) + (wbase >> 16);
    unsigned offp = (excl & 0xFFFFu) + (wbase & 0xFFFFu);

#pragma unroll
    for (int it = 0; it < 4; it++) {
#pragma unroll
        for (int c = 0; c < 4; c++) {
            float x = (c == 0) ? xv[it].x : (c == 1) ? xv[it].y : (c == 2) ? xv[it].z : xv[it].w;
            int   t = (c == 0) ? tv[it].x : (c == 1) ? tv[it].y : (c == 2) ? tv[it].z : tv[it].w;
            const int li = (threadIdx.x + it * 256) * 4 + c;
            if (t > 0) lpos[offp++] = (unsigned short)li;
            else if (x >= XC) lcand[offc++] = x;
        }
    }
    __syncthreads();

    // coalesced plain publish (kernel boundary provides coherence)
    float* seg = (float*)(ws + OFF_CAND) + (size_t)block * CHUNK;
    for (unsigned i = threadIdx.x; i < totc; i += 256) seg[i] = lcand[i];

    double sl1 = 0.0;
    for (unsigned i = threadIdx.x; i < totp; i += 256) {
        const int e = base + (int)lpos[i];
        sl1 += (double)smooth_l1_4(loc4[e], loct4[e]);
    }

    double s1 = wredD(sl1), s2 = wredD(bcp);
    if (lane == 0) { wrD[wid] = s1; wrD[4 + wid] = s2; }
    __syncthreads();
    if (threadIdx.x == 0) {
        ((double*)(ws + OFF_SL1P))[block] = wrD[0] + wrD[1] + wrD[2] + wrD[3];
        ((double*)(ws + OFF_BCEP))[block] = wrD[4] + wrD[5] + wrD[6] + wrD[7];
        ((unsigned*)(ws + OFF_NP))[block] = totp;
        ((unsigned*)(ws + OFF_CC))[block] = totc;
    }
}

// ===================== K2: per-row selection (64 blocks, plain loads) =====================
__global__ void __launch_bounds__(256)
mbl_k2(const float* __restrict__ conf, const int* __restrict__ conft,
       unsigned char* __restrict__ ws)
{
    __shared__ unsigned hist[HBINS];     // 16 KB
    __shared__ float ubuf[CJCAP];        // 4 KB
    __shared__ unsigned wsuf[4], sccS[BPR];
    __shared__ double wrD[4];
    __shared__ int shI[4];
    __shared__ unsigned shJ, shRemJ, shNP, shT, shCj;

    const int row = blockIdx.x;
    const int lane = threadIdx.x & 63, wid = threadIdx.x >> 6;

    // per-segment counts (k1 outputs, boundary-coherent plain loads)
    if (wid == 0) {
        const unsigned* ccp = (const unsigned*)(ws + OFF_CC) + row * BPR;
        const unsigned* npp = (const unsigned*)(ws + OFF_NP) + row * BPR;
        unsigned c = (lane < BPR) ? ccp[lane] : 0u;
        unsigned p = (lane < BPR) ? npp[lane] : 0u;
        if (lane < BPR) sccS[lane] = c;
        unsigned ct = c, pt = p;
#pragma unroll
        for (int o = 1; o < BPR; o <<= 1) {
            ct += __shfl_down(ct, o, 64);
            pt += __shfl_down(pt, o, 64);
        }
        if (lane == 0) { shT = ct; shNP = pt; shCj = 0; }
    }
    __syncthreads();

    const int np = (int)shNP;
    const unsigned n = shT;
    long long k = (long long)np * NEGPOS;
    if (k > D_) k = D_;
    long long negs = (long long)D_ - np;
    if (k > negs) k = negs;
    if (threadIdx.x == 0) ((int*)(ws + OFF_KSEL))[row] = (int)k;

    bool done = false, fb = false;
    if (k <= 0) {
        if (threadIdx.x == 0) ((double*)(ws + OFF_NEGSUM))[row] = 0.0;
        done = true;
    } else if ((long long)n < k) {
        fb = true;                        // not enough candidates above XC
    }

    if (!done && !fb) {
        const int s = threadIdx.x >> 4, li = threadIdx.x & 15;
        const unsigned cs = sccS[s];
        const float4* seg4 = (const float4*)((const float*)(ws + OFF_CAND)
                             + (size_t)(row * BPR + s) * CHUNK);

        for (int i = threadIdx.x; i < HBINS; i += 256) hist[i] = 0;
        __syncthreads();

        // pass 1: plain float4 stream (compiler-pipelined) -> LDS histogram
        for (unsigned i0 = (unsigned)li * 4u; i0 < cs; i0 += 64u) {
            const float4 q = seg4[i0 >> 2];
            if (i0 + 0 < cs) atomicAdd(&hist[bin_of_x(q.x)], 1u);
            if (i0 + 1 < cs) atomicAdd(&hist[bin_of_x(q.y)], 1u);
            if (i0 + 2 < cs) atomicAdd(&hist[bin_of_x(q.z)], 1u);
            if (i0 + 3 < cs) atomicAdd(&hist[bin_of_x(q.w)], 1u);
        }
        __syncthreads();

        // parallel suffix scan over 4096 bins -> threshold bin J, remJ
        unsigned s16 = 0;
        const int b0i = threadIdx.x * 16;
#pragma unroll
        for (int j = 0; j < 16; j++) s16 += hist[b0i + j];
        unsigned suf = s16;
#pragma unroll
        for (int o = 1; o < 64; o <<= 1) {
            unsigned v = __shfl_down(suf, o, 64);
            if (lane + o < 64) suf += v;
        }
        if (lane == 0) wsuf[wid] = suf;
        __syncthreads();
        unsigned addw = 0;
        for (int w = wid + 1; w < 4; w++) addw += wsuf[w];
        suf += addw;
        const unsigned sufx = suf - s16;
        if ((long long)sufx < k && (long long)suf >= k) {
            long long cum = sufx;
            for (int j = 15; j >= 0; j--) {
                cum += hist[b0i + j];
                if (cum >= k) {
                    shJ = (unsigned)(b0i + j);
                    shRemJ = (unsigned)(k - (cum - (long long)hist[b0i + j]));
                    break;
                }
            }
        }
        __syncthreads();
        const unsigned J = shJ, remJ = shRemJ;

        // pass 2: stream again; softplus-sum bins > J, gather bin-J values
        double acc = 0.0;
        for (unsigned i0 = (unsigned)li * 4u; i0 < cs; i0 += 64u) {
            const float4 q = seg4[i0 >> 2];
#pragma unroll
            for (int c = 0; c < 4; c++) {
                if (i0 + (unsigned)c < cs) {
                    const float x = (c == 0) ? q.x : (c == 1) ? q.y : (c == 2) ? q.z : q.w;
                    const int b = bin_of_x(x);
                    if (b > (int)J) acc += (double)softplus_f(x);
                    else if (b == (int)J) {
                        unsigned sl = atomicAdd(&shCj, 1u);
                        if (sl < CJCAP) ubuf[sl] = x;
                    }
                }
            }
        }
        __syncthreads();
        const unsigned cj = shCj;

        if (cj <= CJCAP) {
            // exact rank-select inside bin J (ties equal values -> selected
            // multiset independent of nondeterministic slot order)
            for (unsigned i = threadIdx.x; i < cj; i += 256) {
                const float xi = ubuf[i];
                unsigned r = 0;
                for (unsigned l = 0; l < cj; l++) {
                    const float xl = ubuf[l];
                    r += (xl > xi || (xl == xi && l < i)) ? 1u : 0u;
                }
                if (r < remJ) acc += (double)softplus_f(xi);
            }
            double t = wredD(acc);
            if (lane == 0) wrD[wid] = t;
            __syncthreads();
            if (threadIdx.x == 0)
                ((double*)(ws + OFF_NEGSUM))[row] =
                    wrD[0] + wrD[1] + wrD[2] + wrD[3];
            done = true;
        } else fb = true;   // pathological mass-tie
    }

    if (!done && fb) {
        // exact uint-bisection over the full row (plain cached input loads)
        const float* rowc = conf + row * D_;
        const int*   rowt = conft + row * D_;
        unsigned lo = 0u, hi = 0xFFFFFFFFu;
        for (int it = 0; it < 32; it++) {
            const unsigned mid = lo + ((hi - lo) >> 1);
            unsigned um = (mid & 0x80000000u) ? (mid & 0x7FFFFFFFu) : ~mid;
            float fm = __uint_as_float(um);
            int c = 0;
            for (int i = threadIdx.x; i < D_; i += 256)
                if (rowt[i] <= 0 && rowc[i] > fm) c++;
            const int tot = blockSumI(c, shI);
            if ((long long)tot >= k) lo = mid; else hi = mid;
        }
        unsigned uT = (hi & 0x80000000u) ? (hi & 0x7FFFFFFFu) : ~hi;
        float xT = __uint_as_float(uT);
        int c = 0;
        double acc = 0.0;
        for (int i = threadIdx.x; i < D_; i += 256) {
            if (rowt[i] <= 0) {
                float x = rowc[i];
                if (x > xT) { c++; acc += (double)softplus_f(x); }
            }
        }
        int rem = (int)(k - (long long)blockSumI(c, shI));
        double t = wredD(acc);
        if (lane == 0) wrD[wid] = t;
        __syncthreads();
        if (threadIdx.x == 0)
            ((double*)(ws + OFF_NEGSUM))[row] =
                wrD[0] + wrD[1] + wrD[2] + wrD[3] +
                (double)rem * (double)softplus_f(xT);
    }
}

// ===================== K5: final reduce (1 block, R7-proven) =====================
__global__ void __launch_bounds__(256)
mbl_k5(unsigned char* __restrict__ ws, float* __restrict__ out)
{
    __shared__ double wrA[4], wrB[4], wrC[4];
    __shared__ int shN[4], shK[4];
    const double* sl1p = (const double*)(ws + OFF_SL1P);
    const double* bcep = (const double*)(ws + OFF_BCEP);
    const unsigned* npb = (const unsigned*)(ws + OFF_NP);
    const int* ksel = (const int*)(ws + OFF_KSEL);
    const double* ns = (const double*)(ws + OFF_NEGSUM);

    double a = 0.0, b = 0.0, c = 0.0;
    int n = 0, kk = 0;
    for (int i = threadIdx.x; i < NBLK; i += 256) {
        a += sl1p[i]; b += bcep[i]; n += (int)npb[i];
    }
    if (threadIdx.x < B_) { kk = ksel[threadIdx.x]; c = ns[threadIdx.x]; }

    double ra = wredD(a), rb = wredD(b), rc = wredD(c);
    int rn = wredI(n), rk = wredI(kk);
    const int lane = threadIdx.x & 63, wid = threadIdx.x >> 6;
    if (lane == 0) { wrA[wid] = ra; wrB[wid] = rb; wrC[wid] = rc; shN[wid] = rn; shK[wid] = rk; }
    __syncthreads();
    if (threadIdx.x == 0) {
        double SL1 = wrA[0] + wrA[1] + wrA[2] + wrA[3];
        double BCE = wrB[0] + wrB[1] + wrB[2] + wrB[3];
        double NSUM = wrC[0] + wrC[1] + wrC[2] + wrC[3];
        double Np = (double)(shN[0] + shN[1] + shN[2] + shN[3]);
        double Kt = (double)(shK[0] + shK[1] + shK[2] + shK[3]);
        double out0 = (Np > 0.0) ? (SL1 / (4.0 * Np)) / Np : 0.0;
        double denom = Np + Kt;
        double out1 = (Np > 0.0 && denom > 0.0) ? ((BCE + NSUM) / denom) / Np : 0.0;
        out[0] = (float)out0;
        out[1] = (float)out1;
    }
}

extern "C" void kernel_launch(void* const* d_in, const int* in_sizes, int n_in,
                              void* d_out, int out_size, void* d_ws, size_t ws_size,
                              hipStream_t stream)
{
    const float4* loc4  = (const float4*)d_in[0];   // (B,D,4) f32
    const float*  conf  = (const float*)d_in[1];    // (B,D,1) f32
    const float4* loct4 = (const float4*)d_in[2];   // (B,D,4) f32
    const int*    conft = (const int*)d_in[3];      // (B,D)   i32
    unsigned char* ws = (unsigned char*)d_ws;
    float* out = (float*)d_out;

    mbl_k1<<<dim3(NBLK), dim3(256), 0, stream>>>(loc4, conf, loct4, conft, ws);
    mbl_k2<<<dim3(B_), dim3(256), 0, stream>>>(conf, conft, ws);
    mbl_k5<<<dim3(1), dim3(256), 0, stream>>>(ws, out);
}

// Round 11
// 168.130 us; speedup vs baseline: 1.3818x; 1.0389x over previous
//
#include <hip/hip_runtime.h>
#include <stdint.h>

// MultiBoxLoss: B=64 rows, D=65536 anchors, ~2% positives.
// R18 = R16's design, re-expressed to change the binary after the identical
// R16/R17 source failed the container twice (while the different R15 passed
// in between). Audit found no kernel fault; hedging against a codegen/infra
// interaction by removing every construct that differs from proven-passing
// code: (1) no u16 hist packing (plain u32); (2) hist/bsum built from the
// LDS-compacted lcand AFTER the scatter barrier (~2 iters/thread) so the
// R15-proven scatter loop is byte-identical and the LDS atomics live in a
// trivial loop; (3) no unroll pragma on k2's merge; (4) k2 gather/rank-
// select/bisection fallback copied verbatim from R15's passing binary.
//
// Design recap (unchanged): the ~30us k2 tail is invariant across FIVE
// implementations because it's the WORK (two full streams over ~6.9k
// candidates/row at 64-block parallelism + ~2600 softplus/row). k1's 1024
// blocks already hold the candidates in LDS, so k1 builds per-block:
//   lhist[512] u32 counts, lbsum[512] u64 fixed-point (2^38) softplus sums
//   (integer adds commute -> deterministic)
// and writes both coalesced (+6MB ~ +1us BW). k2 collapses to: merge
// 16x512 hist/bsum (96KB coalesced), 512-bin suffix scan, NEG = sum of
// bins > J, ONE filter pass gathering ~70 bin-J members, exact rank-select.
// Numerics: fixed-point quantization ~1e-12 rel on NEG; bin J exact in f64;
// fallback (n<k or bin-J overflow) = exact bisection.
// No elections / no asm / no __hip_atomic / no memset (R15 proven shell).

#define B_ 64
#define D_ 65536
#define NEGPOS 3
#define BPR 16                 // k1 blocks per row
#define NBLK (B_ * BPR)        // 1024
#define CHUNK (D_ / BPR)       // 4096 elements per k1 block
#define XC 1.25f               // candidate cutoff (P(x>=XC)~10.6% per row)
#define HB512 512              // histogram bins over x in [XC, XC+XRANGE)
#define XRANGE 5.0f
#define CJCAP 1024             // bin-J gather capacity (expect ~70 at 512 bins)

#define FXS 274877906944.0     // 2^38 fixed-point scale
#define FXI (1.0 / 274877906944.0)

typedef unsigned long long ull;

// ---------------- ws layout (bytes), nothing needs zeroing ----------------
#define OFF_SL1P   0           // double[NBLK]        (k1 -> k5)
#define OFF_BCEP   8192        // double[NBLK]        (k1 -> k5)
#define OFF_NP     16384       // u32[NBLK]           (k1 -> k2,k5)
#define OFF_CC     20480       // u32[NBLK]           (k1 -> k2)
#define OFF_NEGSUM 24576       // double[64]          (k2 -> k5)
#define OFF_KSEL   25088       // int[64]             (k2 -> k5)
#define OFF_HIST   32768       // u32[NBLK][512] = 2 MiB   (k1 -> k2)
#define OFF_BSUM   2129920     // u64[NBLK][512] = 4 MiB   (k1 -> k2), ends 6324224
#define OFF_CAND   8388608     // f32[NBLK][CHUNK] = 16 MiB (k1 -> k2), ends 24 MiB

__device__ __forceinline__ float softplus_f(float x) {   // bce for t=0
    return fmaxf(x, 0.0f) + log1pf(expf(-fabsf(x)));
}

__device__ __forceinline__ int bin_of_x(float x) {
    int b = (int)((x - XC) * ((float)HB512 / XRANGE));
    return max(0, min(HB512 - 1, b));
}

__device__ __forceinline__ float smooth_l1_4(float4 a, float4 b) {
    float s = 0.0f, d, ad;
    d = a.x - b.x; ad = fabsf(d); s += (ad < 1.0f) ? 0.5f * d * d : ad - 0.5f;
    d = a.y - b.y; ad = fabsf(d); s += (ad < 1.0f) ? 0.5f * d * d : ad - 0.5f;
    d = a.z - b.z; ad = fabsf(d); s += (ad < 1.0f) ? 0.5f * d * d : ad - 0.5f;
    d = a.w - b.w; ad = fabsf(d); s += (ad < 1.0f) ? 0.5f * d * d : ad - 0.5f;
    return s;
}

__device__ __forceinline__ double wredD(double v) {
#pragma unroll
    for (int o = 32; o > 0; o >>= 1) v += __shfl_down(v, o, 64);
    return v;
}
__device__ __forceinline__ int wredI(int v) {
#pragma unroll
    for (int o = 32; o > 0; o >>= 1) v += __shfl_down(v, o, 64);
    return v;
}
__device__ __forceinline__ ull wredU64(ull v) {
#pragma unroll
    for (int o = 32; o > 0; o >>= 1) v += __shfl_down(v, o, 64);
    return v;
}

__device__ __forceinline__ int blockSumI(int v, int* sh) {
    int w = wredI(v);
    const int lane = threadIdx.x & 63, wid = threadIdx.x >> 6;
    __syncthreads();
    if (lane == 0) sh[wid] = w;
    __syncthreads();
    return sh[0] + sh[1] + sh[2] + sh[3];
}

// ===================== K1: per-chunk pass (1024 blocks) =====================
__global__ void __launch_bounds__(256)
mbl_k1(const float4* __restrict__ loc4, const float* __restrict__ conf,
       const float4* __restrict__ loct4, const int* __restrict__ conft,
       unsigned char* __restrict__ ws)
{
    __shared__ float lcand[CHUNK];           // 16 KB
    __shared__ unsigned short lpos[CHUNK];   // 8 KB
    __shared__ unsigned lhist[HB512];        // 2 KB
    __shared__ ull lbsum[HB512];             // 4 KB
    __shared__ unsigned wtot[4];
    __shared__ double wrD[8];

    const int block = blockIdx.x;
    const int base = block * CHUNK;
    const int tid = threadIdx.x;
    const int lane = tid & 63, wid = tid >> 6;

    // zero per-block hist + bin sums (ordered before the atomics below by
    // the prefix-scan __syncthreads)
    lhist[tid] = 0u;       lhist[tid + 256] = 0u;
    lbsum[tid] = 0ull;     lbsum[tid + 256] = 0ull;

    const float4* c4 = (const float4*)(conf + base);
    const int4*   t4 = (const int4*)(conft + base);

    float4 xv[4]; int4 tv[4];
#pragma unroll
    for (int it = 0; it < 4; it++) {
        const int g = tid + it * 256;
        xv[it] = c4[g];
        tv[it] = t4[g];
    }

    double bcp = 0.0;
    unsigned cntc = 0, cntp = 0;
#pragma unroll
    for (int it = 0; it < 4; it++) {
#pragma unroll
        for (int c = 0; c < 4; c++) {
            float x = (c == 0) ? xv[it].x : (c == 1) ? xv[it].y : (c == 2) ? xv[it].z : xv[it].w;
            int   t = (c == 0) ? tv[it].x : (c == 1) ? tv[it].y : (c == 2) ? tv[it].z : tv[it].w;
            if (t > 0) { cntp++; bcp += (double)(softplus_f(x) - x); }
            else if (x >= XC) cntc++;
        }
    }

    unsigned pk = (cntc << 16) | cntp;
    unsigned incl = pk;
#pragma unroll
    for (int o = 1; o < 64; o <<= 1) {
        unsigned v = __shfl_up(incl, o, 64);
        if (lane >= o) incl += v;
    }
    unsigned excl = incl - pk;
    if (lane == 63) wtot[wid] = incl;
    __syncthreads();
    unsigned wbase = 0;
    for (int w = 0; w < wid; w++) wbase += wtot[w];
    const unsigned tot = wtot[0] + wtot[1] + wtot[2] + wtot[3];
    const unsigned totc = tot >> 16, totp = tot & 0xFFFFu;
    unsigned offc = (excl >> 16) + (wbase >> 16);
    unsigned offp = (excl & 0xFFFFu) + (wbase & 0xFFFFu);

    // scatter loop: byte-identical to R15's proven form (no atomics inside)
#pragma unroll
    for (int it = 0; it < 4; it++) {
#pragma unroll
        for (int c = 0; c < 4; c++) {
            float x = (c == 0) ? xv[it].x : (c == 1) ? xv[it].y : (c == 2) ? xv[it].z : xv[it].w;
            int   t = (c == 0) ? tv[it].x : (c == 1) ? tv[it].y : (c == 2) ? tv[it].z : tv[it].w;
            const int li = (tid + it * 256) * 4 + c;
            if (t > 0) lpos[offp++] = (unsigned short)li;
            else if (x >= XC) lcand[offc++] = x;
        }
    }
    __syncthreads();

    // coalesced plain publish (kernel boundary provides coherence)
    float* seg = (float*)(ws + OFF_CAND) + (size_t)block * CHUNK;
    for (unsigned i = tid; i < totc; i += 256) seg[i] = lcand[i];

    // hist + fixed-point softplus bin-sums from the compacted LDS list
    // (~2 iterations/thread; LDS atomics, no global traffic)
    for (unsigned i = tid; i < totc; i += 256) {
        const float x = lcand[i];
        const int b = bin_of_x(x);
        atomicAdd(&lhist[b], 1u);
        atomicAdd(&lbsum[b], (ull)((double)softplus_f(x) * FXS + 0.5));
    }

    double sl1 = 0.0;
    for (unsigned i = tid; i < totp; i += 256) {
        const int e = base + (int)lpos[i];
        sl1 += (double)smooth_l1_4(loc4[e], loct4[e]);
    }

    double s1 = wredD(sl1), s2 = wredD(bcp);
    if (lane == 0) { wrD[wid] = s1; wrD[4 + wid] = s2; }
    __syncthreads();   // orders: hist/bsum atomics AND wrD before writeout

    // coalesced hist/bsum writeout
    {
        unsigned* gh = (unsigned*)(ws + OFF_HIST) + (size_t)block * HB512;
        ull*      gb = (ull*)(ws + OFF_BSUM) + (size_t)block * HB512;
        gh[tid]       = lhist[tid];
        gh[tid + 256] = lhist[tid + 256];
        gb[tid]       = lbsum[tid];
        gb[tid + 256] = lbsum[tid + 256];
    }

    if (tid == 0) {
        ((double*)(ws + OFF_SL1P))[block] = wrD[0] + wrD[1] + wrD[2] + wrD[3];
        ((double*)(ws + OFF_BCEP))[block] = wrD[4] + wrD[5] + wrD[6] + wrD[7];
        ((unsigned*)(ws + OFF_NP))[block] = totp;
        ((unsigned*)(ws + OFF_CC))[block] = totc;
    }
}

// ===================== K2: per-row selection (64 blocks, thin) =====================
__global__ void __launch_bounds__(256)
mbl_k2(const float* __restrict__ conf, const int* __restrict__ conft,
       unsigned char* __restrict__ ws)
{
    __shared__ float ubuf[CJCAP];        // 4 KB
    __shared__ unsigned wsuf[4], sccS[BPR];
    __shared__ double wrD[4];
    __shared__ ull wrU[4];
    __shared__ int shI[4];
    __shared__ unsigned shJ, shRemJ, shNP, shT, shCj, shCJN;

    const int row = blockIdx.x;
    const int tid = threadIdx.x;
    const int lane = tid & 63, wid = tid >> 6;

    // per-segment counts (k1 outputs, boundary-coherent plain loads)
    if (wid == 0) {
        const unsigned* ccp = (const unsigned*)(ws + OFF_CC) + row * BPR;
        const unsigned* npp = (const unsigned*)(ws + OFF_NP) + row * BPR;
        unsigned c = (lane < BPR) ? ccp[lane] : 0u;
        unsigned p = (lane < BPR) ? npp[lane] : 0u;
        if (lane < BPR) sccS[lane] = c;
        unsigned ct = c, pt = p;
#pragma unroll
        for (int o = 1; o < BPR; o <<= 1) {
            ct += __shfl_down(ct, o, 64);
            pt += __shfl_down(pt, o, 64);
        }
        if (lane == 0) { shT = ct; shNP = pt; shCj = 0; }
    }
    __syncthreads();

    const int np = (int)shNP;
    const unsigned n = shT;
    long long k = (long long)np * NEGPOS;
    if (k > D_) k = D_;
    long long negs = (long long)D_ - np;
    if (k > negs) k = negs;
    if (tid == 0) ((int*)(ws + OFF_KSEL))[row] = (int)k;

    bool done = false, fb = false;
    if (k <= 0) {
        if (tid == 0) ((double*)(ws + OFF_NEGSUM))[row] = 0.0;
        done = true;
    } else if ((long long)n < k) {
        fb = true;                        // not enough candidates above XC
    }

    if (!done && !fb) {
        // ---- merge 16 per-segment hists + bsums; thread t owns bins 2t,2t+1
        const unsigned* ghrow = (const unsigned*)(ws + OFF_HIST) + (size_t)row * BPR * HB512;
        const ull*      gbrow = (const ull*)(ws + OFF_BSUM) + (size_t)row * BPR * HB512;
        unsigned rc0 = 0, rc1 = 0;
        ull bs0 = 0, bs1 = 0;
        for (int s = 0; s < BPR; s++) {
            const uint2 h2 = ((const uint2*)(ghrow + s * HB512))[tid];  // 8B coalesced
            rc0 += h2.x; rc1 += h2.y;
            bs0 += gbrow[s * HB512 + 2 * tid];                          // 8B coalesced
            bs1 += gbrow[s * HB512 + 2 * tid + 1];
        }

        // ---- suffix scan over 512 bins (2 bins/thread) -> bin J, remJ
        const unsigned s2 = rc0 + rc1;
        unsigned suf = s2;
#pragma unroll
        for (int o = 1; o < 64; o <<= 1) {
            unsigned v = __shfl_down(suf, o, 64);
            if (lane + o < 64) suf += v;
        }
        if (lane == 0) wsuf[wid] = suf;
        __syncthreads();
        unsigned addw = 0;
        for (int w = wid + 1; w < 4; w++) addw += wsuf[w];
        suf += addw;                          // count in bins >= 2*tid
        const unsigned sufx = suf - s2;       // count in bins >  2*tid+1
        if ((long long)sufx < k && (long long)suf >= k) {
            const long long cum = (long long)sufx + rc1;   // count >= bin 2t+1
            if (cum >= k) { shJ = 2 * tid + 1; shRemJ = (unsigned)(k - sufx); shCJN = rc1; }
            else          { shJ = 2 * tid;     shRemJ = (unsigned)(k - cum);  shCJN = rc0; }
        }
        __syncthreads();
        const unsigned J = shJ, remJ = shRemJ, cjn = shCJN;

        if (cjn > CJCAP) {
            fb = true;       // pathological mass-tie in bin J
        } else {
            // NEG over bins > J from the fixed-point sums (registers)
            ull part = 0;
            if (2 * tid > (int)J) part += bs0;
            if (2 * tid + 1 > (int)J) part += bs1;
            ull pw = wredU64(part);
            if (lane == 0) wrU[wid] = pw;

            // ONE filter pass over candidates: gather bin-J members (~70)
            const int s = tid >> 4, li = tid & 15;
            const unsigned cs = sccS[s];
            const float4* seg4 = (const float4*)((const float*)(ws + OFF_CAND)
                                 + (size_t)(row * BPR + s) * CHUNK);
            for (unsigned i0 = (unsigned)li * 4u; i0 < cs; i0 += 64u) {
                const float4 q = seg4[i0 >> 2];
#pragma unroll
                for (int c = 0; c < 4; c++) {
                    if (i0 + (unsigned)c < cs) {
                        const float x = (c == 0) ? q.x : (c == 1) ? q.y : (c == 2) ? q.z : q.w;
                        if ((unsigned)bin_of_x(x) == J) {
                            unsigned sl = atomicAdd(&shCj, 1u);
                            if (sl < CJCAP) ubuf[sl] = x;
                        }
                    }
                }
            }
            __syncthreads();
            const unsigned cj = shCj;   // == cjn (same bin fn on same bits)

            // exact rank-select of top-remJ inside bin J (ties equal values
            // -> selected multiset independent of slot order)
            double acc = 0.0;
            for (unsigned i = tid; i < cj; i += 256) {
                const float xi = ubuf[i];
                unsigned r = 0;
                for (unsigned l = 0; l < cj; l++) {
                    const float xl = ubuf[l];
                    r += (xl > xi || (xl == xi && l < i)) ? 1u : 0u;
                }
                if (r < remJ) acc += (double)softplus_f(xi);
            }
            double t2 = wredD(acc);
            if (lane == 0) wrD[wid] = t2;
            __syncthreads();
            if (tid == 0) {
                const ull NU = wrU[0] + wrU[1] + wrU[2] + wrU[3];
                const double CJ = wrD[0] + wrD[1] + wrD[2] + wrD[3];
                ((double*)(ws + OFF_NEGSUM))[row] = (double)NU * FXI + CJ;
            }
            done = true;
        }
    }

    if (!done && fb) {
        // exact uint-bisection over the full row (plain cached input loads)
        const float* rowc = conf + row * D_;
        const int*   rowt = conft + row * D_;
        unsigned lo = 0u, hi = 0xFFFFFFFFu;
        for (int it = 0; it < 32; it++) {
            const unsigned mid = lo + ((hi - lo) >> 1);
            unsigned um = (mid & 0x80000000u) ? (mid & 0x7FFFFFFFu) : ~mid;
            float fm = __uint_as_float(um);
            int c = 0;
            for (int i = tid; i < D_; i += 256)
                if (rowt[i] <= 0 && rowc[i] > fm) c++;
            const int tot = blockSumI(c, shI);
            if ((long long)tot >= k) lo = mid; else hi = mid;
        }
        unsigned uT = (hi & 0x80000000u) ? (hi & 0x7FFFFFFFu) : ~hi;
        float xT = __uint_as_float(uT);
        int c = 0;
        double acc = 0.0;
        for (int i = tid; i < D_; i += 256) {
            if (rowt[i] <= 0) {
                float x = rowc[i];
                if (x > xT) { c++; acc += (double)softplus_f(x); }
            }
        }
        int rem = (int)(k - (long long)blockSumI(c, shI));
        double t2 = wredD(acc);
        if (lane == 0) wrD[wid] = t2;
        __syncthreads();
        if (tid == 0)
            ((double*)(ws + OFF_NEGSUM))[row] =
                wrD[0] + wrD[1] + wrD[2] + wrD[3] +
                (double)rem * (double)softplus_f(xT);
    }
}

// ===================== K5: final reduce (1 block, proven) =====================
__global__ void __launch_bounds__(256)
mbl_k5(unsigned char* __restrict__ ws, float* __restrict__ out)
{
    __shared__ double wrA[4], wrB[4], wrC[4];
    __shared__ int shN[4], shK[4];
    const double* sl1p = (const double*)(ws + OFF_SL1P);
    const double* bcep = (const double*)(ws + OFF_BCEP);
    const unsigned* npb = (const unsigned*)(ws + OFF_NP);
    const int* ksel = (const int*)(ws + OFF_KSEL);
    const double* ns = (const double*)(ws + OFF_NEGSUM);

    double a = 0.0, b = 0.0, c = 0.0;
    int n = 0, kk = 0;
    for (int i = threadIdx.x; i < NBLK; i += 256) {
        a += sl1p[i]; b += bcep[i]; n += (int)npb[i];
    }
    if (threadIdx.x < B_) { kk = ksel[threadIdx.x]; c = ns[threadIdx.x]; }

    double ra = wredD(a), rb = wredD(b), rc = wredD(c);
    int rn = wredI(n), rk = wredI(kk);
    const int lane = threadIdx.x & 63, wid = threadIdx.x >> 6;
    if (lane == 0) { wrA[wid] = ra; wrB[wid] = rb; wrC[wid] = rc; shN[wid] = rn; shK[wid] = rk; }
    __syncthreads();
    if (threadIdx.x == 0) {
        double SL1 = wrA[0] + wrA[1] + wrA[2] + wrA[3];
        double BCE = wrB[0] + wrB[1] + wrB[2] + wrB[3];
        double NSUM = wrC[0] + wrC[1] + wrC[2] + wrC[3];
        double Np = (double)(shN[0] + shN[1] + shN[2] + shN[3]);
        double Kt = (double)(shK[0] + shK[1] + shK[2] + shK[3]);
        double out0 = (Np > 0.0) ? (SL1 / (4.0 * Np)) / Np : 0.0;
        double denom = Np + Kt;
        double out1 = (Np > 0.0 && denom > 0.0) ? ((BCE + NSUM) / denom) / Np : 0.0;
        out[0] = (float)out0;
        out[1] = (float)out1;
    }
}

extern "C" void kernel_launch(void* const* d_in, const int* in_sizes, int n_in,
                              void* d_out, int out_size, void* d_ws, size_t ws_size,
                              hipStream_t stream)
{
    const float4* loc4  = (const float4*)d_in[0];   // (B,D,4) f32
    const float*  conf  = (const float*)d_in[1];    // (B,D,1) f32
    const float4* loct4 = (const float4*)d_in[2];   // (B,D,4) f32
    const int*    conft = (const int*)d_in[3];      // (B,D)   i32
    unsigned char* ws = (unsigned char*)d_ws;
    float* out = (float*)d_out;

    mbl_k1<<<dim3(NBLK), dim3(256), 0, stream>>>(loc4, conf, loct4, conft, ws);
    mbl_k2<<<dim3(B_), dim3(256), 0, stream>>>(conf, conft, ws);
    mbl_k5<<<dim3(1), dim3(256), 0, stream>>>(ws, out);
}